// Round 11
// baseline (1694.360 us; speedup 1.0000x reference)
//
#include <hip/hip_runtime.h>

// Autoregressive masked net sampler.
//  - output col i == sampling-time x[:,i]  (masks: out i depends on spins < i only)
//  - spin blocks of KB=8: history part = dense GEMM (MFMA f16), intra-block part
//    sequential per-row (rows independent -> no grid sync).
// R9: split kernels (hist | seq), 1154us verified. R10-R13: fusion abandoned
//     (compiler caps 8-wave WGs at 60-64 VGPR; seq wave spills on zero-TLP chain).
// R14: hist K-split x2 CONFIRMED (hist left top-5); seq t-loop roll REFUTED
//     (41->69us): R9's full unroll was the latency-hiding mechanism (compiler
//     hoists all 48 phases' weight/Zg loads); rolling killed cross-t hoisting and
//     1-phase-ahead manual prefetch (~300cy) can't cover L3 (~600-900cy).
// R15 (this): seq reverted to exact R9 unrolled structure, only change = sum the
//     two K-split Zg/Zg6 partials (hoistable under unroll). hist keeps K-split.

#define NS   64          // spins
#define HC   20          // hidden channels per spin
#define HTOT 1280        // NS*HC
#define NB   16384       // batch
#define KB   8           // spins per block (8 blocks)
#define BT   16          // batch rows per seq workgroup (MFMA N-tile)

typedef _Float16 f16;
typedef _Float16 f16x2 __attribute__((ext_vector_type(2)));
typedef _Float16 f16x4 __attribute__((ext_vector_type(4)));
typedef _Float16 f16x8 __attribute__((ext_vector_type(8)));
typedef float f32x4 __attribute__((ext_vector_type(4)));
typedef unsigned int u32x4 __attribute__((ext_vector_type(4)));

static __device__ __forceinline__ float sigm(float z) {
  return __builtin_amdgcn_rcpf(1.0f + __expf(-z));
}

static __device__ __forceinline__ unsigned pk2(float a, float b) {
  f16x2 t;
  t[0] = (f16)a;
  t[1] = (f16)b;
  return __builtin_bit_cast(unsigned, t);
}

// ---------------------------------------------------------------------------
// prep: build masked f16 weights, pre-swizzled to MFMA A-fragment order.
// Fragment order: lane = quad*16 + row15, elems 8; col = ks*32 + quad*8 + e.
//  WpT [L][rt=row/16][ks=0..39][512]    row=j_o*20+ch_o, mask j_i<=j_o (hist A)
//  WsT [L][i][tile=ch/16][ks=0..4][512] cols rel to HC*(i&~7), ch padded ->32 (seq A)
//  W1T [i][tile][ks=0..1][512]          cols = spins, mask c<i (seq L1 A)
//  W6bT[m*8+t][512]                     16 tp rows x 32 k, mask t<=tp,k<20 (z6 A)
//  W6T [m][ks=0..39][512]               16 tp rows (8 real), mask j_i<=I+tp
// ---------------------------------------------------------------------------
__global__ __launch_bounds__(256) void prep(
    const float* __restrict__ W1, const float* __restrict__ W2,
    const float* __restrict__ W3, const float* __restrict__ W4,
    const float* __restrict__ W5, const float* __restrict__ W6,
    f16* __restrict__ WpT, f16* __restrict__ WsT, f16* __restrict__ W1T,
    f16* __restrict__ W6bT, f16* __restrict__ W6T) {
  __shared__ float row[HTOT];
  int bid = blockIdx.x;
  if (bid < 4 * HTOT) {
    int L = bid / HTOT, cp = bid % HTOT;
    int j_o = cp / HC, ch_o = cp % HC;
    const float* Wsrc = (L == 0) ? W2 : (L == 1) ? W3 : (L == 2) ? W4 : W5;
    const float* src = Wsrc + (size_t)(ch_o * NS + j_o) * HTOT;
    for (int k = threadIdx.x; k < HTOT; k += 256) row[k] = src[k];
    __syncthreads();
    // WpT: this source row is A-row cp -> rt = cp>>4, row15 = cp&15
    {
      int rt = cp >> 4, rl = cp & 15;
      f16* dwp = WpT + (size_t)(L * 80 + rt) * 40 * 512;
      for (int xp = threadIdx.x; xp < HTOT; xp += 256) {
        int j_i = xp / HC, ch_i = xp % HC;
        f16 v = (f16)((j_i <= j_o) ? row[ch_i * NS + j_i] : 0.0f);
        int ks = xp >> 5, q = (xp >> 3) & 3, e = xp & 7;
        dwp[ks * 512 + (q * 16 + rl) * 8 + e] = v;
      }
    }
    // WsT: A-row ch_o of spin j_o, cols relative to block base HC*(j_o&~7)
    {
      int base = HC * (j_o & ~7);
      int tile = ch_o >> 4, tl = ch_o & 15;
      f16* dws = WsT + (size_t)(((L * NS + j_o) * 2 + tile) * 5) * 512;
      for (int kr = threadIdx.x; kr < 160; kr += 256) {
        int xp = base + kr;
        int j_i = xp / HC, ch_i = xp % HC;
        f16 v = (f16)((j_i <= j_o) ? row[ch_i * NS + j_i] : 0.0f);
        int ks = kr >> 5, q = (kr >> 3) & 3, e = kr & 7;
        dws[ks * 512 + (q * 16 + tl) * 8 + e] = v;
      }
      if (ch_o < 12) {  // zero pad rows ch=20..31 (tile1 rows 4..15)
        int zl = (20 + ch_o) & 15;
        f16* dz = WsT + (size_t)(((L * NS + j_o) * 2 + 1) * 5) * 512;
        for (int kr = threadIdx.x; kr < 160; kr += 256) {
          int ks = kr >> 5, q = (kr >> 3) & 3, e = kr & 7;
          dz[ks * 512 + (q * 16 + zl) * 8 + e] = (f16)0.0f;
        }
      }
    }
  } else if (bid < 4 * HTOT + NS) {
    int j_o = bid - 4 * HTOT;
    for (int idx = threadIdx.x; idx < 32 * 64; idx += 256) {
      int ch = idx >> 6, c = idx & 63;
      float v = (ch < HC && c < j_o) ? W1[((size_t)ch * NS + j_o) * NS + c] : 0.0f;
      int tile = ch >> 4, tl = ch & 15, ks = c >> 5, q = (c >> 3) & 3, e = c & 7;
      W1T[(size_t)((j_o * 2 + tile) * 2 + ks) * 512 + (q * 16 + tl) * 8 + e] = (f16)v;
    }
  } else if (bid < 4 * HTOT + NS + 8) {
    int m = bid - (4 * HTOT + NS);
    int I = m * KB;
    for (int idx = threadIdx.x; idx < 8 * 16 * 32; idx += 256) {
      int t = idx >> 9, tp = (idx >> 5) & 15, k = idx & 31;
      float v = (tp < 8 && k < HC && t <= tp)
                    ? W6[(size_t)(I + tp) * HTOT + k * NS + (I + t)]
                    : 0.0f;
      int q = k >> 3, e = k & 7;
      W6bT[(size_t)(m * 8 + t) * 512 + (q * 16 + tp) * 8 + e] = (f16)v;
    }
  } else {
    int m = bid - (4 * HTOT + NS + 8);
    int I = m * KB;
    for (int idx = threadIdx.x; idx < 16 * HTOT; idx += 256) {
      int tp = idx / HTOT, xp = idx % HTOT;
      int j_i = xp / HC, ch_i = xp % HC;
      float v = (tp < 8 && j_i <= I + tp)
                    ? W6[(size_t)(I + tp) * HTOT + ch_i * NS + j_i]
                    : 0.0f;
      int ks = xp >> 5, q = (xp >> 3) & 3, e = xp & 7;
      W6T[(size_t)(m * 40 + ks) * 512 + (q * 16 + tp) * 8 + e] = (f16)v;
    }
  }
}

// ---------------------------------------------------------------------------
// gemm_hist: history GEMMs for block at spin I; K-split x2 via blockIdx.z.
//  L<4 : ZgP[z][L][c][b]  partial over ks in [ks0, ks0+kn)
//  L==4: Zg6P[z][tp][b]   same split for the layer-6 rows
// A loads coalesced from fragment-order WpT/W6T; AH is raw B-fragment layout.
// Grid (nr/64, 5, 2) x 256 thr -> 2x blocks of R9 = 20 waves/CU. [R14: confirmed]
// ---------------------------------------------------------------------------
__global__ __launch_bounds__(256) void gemm_hist(
    const f16* __restrict__ WpT, const f16* __restrict__ W6T,
    const f16* __restrict__ AH, float* __restrict__ Zg,
    float* __restrict__ Zg6, int I, int BS) {
  const int L = blockIdx.y;
  const int z = blockIdx.z;
  const int tid = threadIdx.x;
  const int lane = tid & 63;
  const int w = tid >> 6;
  const int l15 = tid & 15;
  const int quad = lane >> 4;
  const int m = I >> 3;
  const int G32 = (HC * I) >> 5;
  const int H0 = G32 >> 1;
  const int ks0 = z ? H0 : 0;
  const int kn = z ? (G32 - H0) : H0;
  float* ZgP = Zg + (size_t)z * 640 * BS;
  float* Zg6P = Zg6 + (size_t)z * 16 * BS;

  if (L == 4) {
    const int b0 = blockIdx.x * 64 + w * 16;
    f32x4 acc = (f32x4){0.f, 0.f, 0.f, 0.f};
    const f16* ap = W6T + ((size_t)(m * 40) + ks0) * 512 + lane * 8;
    const f16* bp = AH + ((size_t)(4 * 160 + 4 * ks0 + quad) * BS + b0 + l15) * 8;
#pragma unroll 2
    for (int ks = 0; ks < kn; ++ks) {
      f16x8 af = *(const f16x8*)ap;
      f16x8 bf = *(const f16x8*)bp;
      acc = __builtin_amdgcn_mfma_f32_16x16x32_f16(af, bf, acc, 0, 0, 0);
      ap += 512;
      bp += (size_t)4 * BS * 8;
    }
#pragma unroll
    for (int r = 0; r < 4; ++r)
      Zg6P[(size_t)(quad * 4 + r) * BS + b0 + l15] = acc[r];
    return;
  }

  const int wm = w & 1, wn = w >> 1;
  const int b0 = blockIdx.x * 64 + wn * 32;

  f32x4 acc[5][2];
#pragma unroll
  for (int mt = 0; mt < 5; ++mt) {
    acc[mt][0] = (f32x4){0.f, 0.f, 0.f, 0.f};
    acc[mt][1] = (f32x4){0.f, 0.f, 0.f, 0.f};
  }

  const f16* ap =
      WpT + ((size_t)((L * 80 + 10 * m + 5 * wm) * 40) + ks0) * 512 + lane * 8;
  const f16* bp = AH + ((size_t)(L * 160 + 4 * ks0 + quad) * BS + b0 + l15) * 8;

#pragma unroll 2
  for (int ks = 0; ks < kn; ++ks) {
    f16x8 bf0 = *(const f16x8*)(bp);
    f16x8 bf1 = *(const f16x8*)(bp + 128);
    f16x8 af[5];
#pragma unroll
    for (int mt = 0; mt < 5; ++mt)
      af[mt] = *(const f16x8*)(ap + (size_t)mt * 40 * 512);
#pragma unroll
    for (int mt = 0; mt < 5; ++mt) {
      acc[mt][0] = __builtin_amdgcn_mfma_f32_16x16x32_f16(af[mt], bf0, acc[mt][0], 0, 0, 0);
      acc[mt][1] = __builtin_amdgcn_mfma_f32_16x16x32_f16(af[mt], bf1, acc[mt][1], 0, 0, 0);
    }
    ap += 512;
    bp += (size_t)4 * BS * 8;
  }

#pragma unroll
  for (int mt = 0; mt < 5; ++mt)
#pragma unroll
    for (int nt = 0; nt < 2; ++nt)
#pragma unroll
      for (int r = 0; r < 4; ++r) {
        int c = wm * 80 + mt * 16 + quad * 4 + r;
        int b = b0 + nt * 16 + l15;
        ZgP[(size_t)(L * 160 + c) * BS + b] = acc[mt][nt][r];
      }
}

// ---------------------------------------------------------------------------
// seq_block v7 (R9 structure, latency-pipelined MFMA phases): 1 wave, BT=16.
// Full t-unroll (cross-t load hoisting is the latency-hiding mechanism — R14
// proved rolling this loop costs +70%); Zg post-added as SUM OF TWO K-SPLIT
// PARTIALS (only change vs R9); u preloaded; z6 via shfl from layer-5 C-regs;
// sampled bit carried in reg and patched into next t's L1 B-frag.
// ---------------------------------------------------------------------------
__global__ __launch_bounds__(64) void seq_block(
    const f16* __restrict__ WsT, const f16* __restrict__ W1T,
    const f16* __restrict__ W6bT, f16* __restrict__ AH,
    const float* __restrict__ Zg, const float* __restrict__ Zg6,
    f16* __restrict__ s_ws, const float* __restrict__ u,
    float* __restrict__ outp, int I, int BS, int b0) {
  __shared__ __align__(16) f16 aL[5][BT][184];   // 29440 B
  __shared__ __align__(16) f16 sL[BT][72];       // 2304 B -> 31744 B total

  const int lane = threadIdx.x;
  const int l15 = lane & 15;            // MFMA col = batch row in WG
  const int quad = lane >> 4;           // MFMA k-group / C row-group
  const int m = I >> 3;
  const int bcol = blockIdx.x * BT + l15;
  const int bg = b0 + bcol;
  const size_t ZgPN = (size_t)640 * BS;   // K-split partial strides
  const size_t Zg6PN = (size_t)16 * BS;

  // early global loads: u for all 8 spins, z6 accumulator init (sum partials)
  float uv[KB];
#pragma unroll
  for (int t = 0; t < KB; ++t) uv[t] = u[(size_t)(I + t) * NB + bg];
  f32x4 acc6;
#pragma unroll
  for (int r = 0; r < 4; ++r) {
    size_t o = (size_t)(quad * 4 + r) * BS + bcol;
    acc6[r] = Zg6[o] + Zg6[Zg6PN + o];
  }

  // zero LDS (masked-weight / K-pad tails must read as 0)
  {
    f16x8 z = {};
    f16x8* pa = (f16x8*)&aL[0][0][0];
    for (int k = lane; k < (5 * BT * 184) / 8; k += 64) pa[k] = z;
    f16x8* ps = (f16x8*)&sL[0][0];
    for (int k = lane; k < (BT * 72) / 8; k += 64) ps[k] = z;
  }
  __syncthreads();

  // load sampled-bit history j < I
  for (int c8 = quad; c8 < (I >> 3); c8 += 4) {
    f16x8 v = *(const f16x8*)(s_ws + (size_t)(blockIdx.x * BT + l15) * NS + c8 * 8);
    *(f16x8*)&sL[l15][c8 * 8] = v;
  }
  __syncthreads();

  float bitv = 0.0f;  // freshest sampled bit (spin I+t-1), per batch-column

#pragma unroll
  for (int t = 0; t < KB; ++t) {
    const int i = I + t;

    // ---- prefetch this t's Zg rows (sum of 2 partials), all 4 layers ----
    float zg0[4][4], zg1[4][4];
#pragma unroll
    for (int L = 0; L < 4; ++L)
#pragma unroll
      for (int r = 0; r < 4; ++r) {
        size_t o0 = (size_t)(L * 160 + t * HC + quad * 4 + r) * BS + bcol;
        zg0[L][r] = Zg[o0] + Zg[ZgPN + o0];
        size_t o1 = (size_t)(L * 160 + t * HC + 16 + r) * BS + bcol;
        zg1[L][r] = (quad == 0) ? (Zg[o1] + Zg[ZgPN + o1]) : 0.f;
      }

    // ---- layer 1: z[32ch x 16b] = W1(i) (32x64) . sL (64x16) ----
    {
      f32x4 z0 = (f32x4){0.f, 0.f, 0.f, 0.f};
      f32x4 z1 = (f32x4){0.f, 0.f, 0.f, 0.f};
      const int KS1 = (i + 31) >> 5;
      const f16* w0 = W1T + (size_t)(i * 2) * 2 * 512 + lane * 8;
      for (int ks = 0; ks < KS1; ++ks) {
        f16x8 bf = *(const f16x8*)&sL[l15][quad * 8 + 32 * ks];
        if (t > 0 && ks == ((i - 1) >> 5) && quad == (((I & 31) + t - 1) >> 3))
          bf[(t - 1) & 7] = (f16)bitv;  // freshest bit, not yet LDS-visible
        f16x8 a0 = *(const f16x8*)(w0 + ks * 512);
        f16x8 a1 = *(const f16x8*)(w0 + (2 + ks) * 512);
        z0 = __builtin_amdgcn_mfma_f32_16x16x32_f16(a0, bf, z0, 0, 0, 0);
        z1 = __builtin_amdgcn_mfma_f32_16x16x32_f16(a1, bf, z1, 0, 0, 0);
      }
      f16x4 o0;
#pragma unroll
      for (int r = 0; r < 4; ++r) o0[r] = (f16)sigm(z0[r]);
      *(f16x4*)&aL[0][l15][t * HC + quad * 4] = o0;
      if (quad == 0) {
        f16x4 o1;
#pragma unroll
        for (int r = 0; r < 4; ++r) o1[r] = (f16)sigm(z1[r]);
        *(f16x4*)&aL[0][l15][t * HC + 16] = o1;
      }
    }
    __syncthreads();

    // ---- layers 2..5: z = W(L,i) (32xK) . aL[L] (Kx16), then += Zg ----
    const int KS = (HC * (t + 1) + 31) >> 5;  // compile-time under unroll
    float a5o0[4], a5o1[4];
#pragma unroll
    for (int L = 0; L < 4; ++L) {
      f32x4 z0 = (f32x4){0.f, 0.f, 0.f, 0.f};
      f32x4 z1 = (f32x4){0.f, 0.f, 0.f, 0.f};
      const f16* wb = WsT + (size_t)((L * NS + i) * 2) * 5 * 512 + lane * 8;
#pragma unroll
      for (int ks = 0; ks < KS; ++ks) {
        f16x8 bf = *(const f16x8*)&aL[L][l15][quad * 8 + 32 * ks];
        f16x8 a0 = *(const f16x8*)(wb + ks * 512);
        f16x8 a1 = *(const f16x8*)(wb + (5 + ks) * 512);
        z0 = __builtin_amdgcn_mfma_f32_16x16x32_f16(a0, bf, z0, 0, 0, 0);
        z1 = __builtin_amdgcn_mfma_f32_16x16x32_f16(a1, bf, z1, 0, 0, 0);
      }
      f16x4 o0;
#pragma unroll
      for (int r = 0; r < 4; ++r) {
        float v = sigm(z0[r] + zg0[L][r]);
        o0[r] = (f16)v;
        if (L == 3) a5o0[r] = v;
      }
      *(f16x4*)&aL[L + 1][l15][t * HC + quad * 4] = o0;
      {
        f16x4 o1;
#pragma unroll
        for (int r = 0; r < 4; ++r) {
          float v = sigm(z1[r] + zg1[L][r]);
          o1[r] = (f16)v;
          if (L == 3) a5o1[r] = v;
        }
        if (quad == 0) *(f16x4*)&aL[L + 1][l15][t * HC + 16] = o1;
      }
      if (L < 3) __syncthreads();  // aL[4] never cross-read before writeout
    }

    // ---- z6: B-frag = fresh a5 only (W6bT zero-masks k>=20) via shfl ----
    {
      unsigned p0 = pk2(a5o0[0], a5o0[1]);
      unsigned p1 = pk2(a5o0[2], a5o0[3]);
      unsigned p2 = pk2(a5o1[0], a5o1[1]);
      unsigned p3 = pk2(a5o1[2], a5o1[3]);
      int src1 = (((quad * 2) & 3) << 4) + l15;
      int src2 = src1 + 16;
      unsigned d0 = (unsigned)__shfl((int)p0, src1, 64);
      unsigned d1 = (unsigned)__shfl((int)p1, src1, 64);
      unsigned d2 = (unsigned)__shfl((int)p0, src2, 64);
      unsigned d3 = (unsigned)__shfl((int)p1, src2, 64);
      unsigned e0 = (unsigned)__shfl((int)p2, src1, 64);
      unsigned e1 = (unsigned)__shfl((int)p3, src1, 64);
      u32x4 bv = (quad < 2) ? (u32x4){d0, d1, d2, d3} : (u32x4){e0, e1, e0, e1};
      f16x8 b5 = __builtin_bit_cast(f16x8, bv);
      f16x8 a6 = *(const f16x8*)(W6bT + (size_t)(m * 8 + t) * 512 + lane * 8);
      acc6 = __builtin_amdgcn_mfma_f32_16x16x32_f16(a6, b5, acc6, 0, 0, 0);
      // extract row t (owner quad = t>>2, reg t&3; static under unroll)
      float x = sigm(acc6[t & 3]);
      if (quad == (t >> 2)) {
        outp[(size_t)bg * NS + i] = x;  // final output col i == sampling-time x
        sL[l15][i] = (f16)((x >= uv[t]) ? 1.0f : -1.0f);
      }
      float xall = __shfl(x, ((t >> 2) << 4) + l15, 64);
      bitv = (xall >= uv[t]) ? 1.0f : -1.0f;
    }
    // no end-of-t barrier: t+1 L1 gets the fresh bit from bitv; older sL writes
    // are >= 4 syncs old; aL[4] writes only read after the final barrier.
  }
  __syncthreads();

  // ---- bulk writeout: block activations -> global AH ([L][g][b][e]), s bits ----
  for (int w = lane; w < 5 * 20 * BT; w += 64) {
    int rr = w & 15;
    int q = w >> 4;            // 0..99
    int L = q / 20, x8 = q % 20;
    f16x8 v = *(const f16x8*)&aL[L][rr][x8 * 8];
    int gg = ((HC * I) >> 3) + x8;
    *(f16x8*)(AH + ((size_t)(L * 160 + gg) * BS + blockIdx.x * BT + rr) * 8) = v;
  }
  if (lane < BT) {
    *(f16x8*)(s_ws + (size_t)(blockIdx.x * BT + lane) * NS + I) =
        *(const f16x8*)&sL[lane][I];
  }
}

// ---------------------------------------------------------------------------
extern "C" void kernel_launch(void* const* d_in, const int* in_sizes, int n_in,
                              void* d_out, int out_size, void* d_ws, size_t ws_size,
                              hipStream_t stream) {
  (void)in_sizes; (void)n_in; (void)out_size;
  const float* u  = (const float*)d_in[1];
  const float* W1 = (const float*)d_in[2];
  const float* W2 = (const float*)d_in[3];
  const float* W3 = (const float*)d_in[4];
  const float* W4 = (const float*)d_in[5];
  const float* W5 = (const float*)d_in[6];
  const float* W6 = (const float*)d_in[7];
  float* outp = (float*)d_out;

  const size_t wpTEls  = (size_t)4 * 80 * 40 * 512;      // 6.55M  hist A
  const size_t wsTEls  = (size_t)4 * NS * 2 * 5 * 512;   // 1.31M  seq A
  const size_t w1TEls  = (size_t)NS * 2 * 2 * 512;       // 131K   seq L1 A
  const size_t w6bTEls = (size_t)64 * 512;               // 33K    seq z6 A
  const size_t w6TEls  = (size_t)8 * 40 * 512;           // 164K   hist z6 A
  const size_t wEls = wpTEls + wsTEls + w1TEls + w6bTEls + w6TEls;
  const size_t wBytes = wEls * sizeof(f16);

  // per-row: AH 12800 + Zg 2x2560 + Zg6 2x64 + s_ws 128 = 18176 B
  size_t rem = (ws_size > wBytes + 4096) ? (ws_size - wBytes - 4096) : 0;
  long long bs = (long long)(rem / 18176);
  bs = (bs / 64) * 64;
  if (bs > NB) bs = NB;
  if (bs < 64) bs = 64;
  const int BS = (int)bs;

  f16* WpT   = (f16*)d_ws;
  f16* WsT   = WpT + wpTEls;
  f16* W1T   = WsT + wsTEls;
  f16* W6bT  = W1T + w1TEls;
  f16* W6T   = W6bT + w6bTEls;
  f16* AH    = W6T + w6TEls;
  float* Zg  = (float*)(AH + (size_t)5 * 160 * BS * 8);
  float* Zg6 = Zg + (size_t)2 * 640 * BS;
  f16* s_ws  = (f16*)(Zg6 + (size_t)2 * 16 * BS);

  prep<<<dim3(4 * HTOT + NS + 16), dim3(256), 0, stream>>>(
      W1, W2, W3, W4, W5, W6, WpT, WsT, W1T, W6bT, W6T);

  for (int c0 = 0; c0 < NB; c0 += BS) {
    int nr = NB - c0; if (nr > BS) nr = BS;
    for (int m = 0; m < NS / KB; ++m) {
      const int I = m * KB;
      gemm_hist<<<dim3(nr / 64, 5, 2), dim3(256), 0, stream>>>(
          WpT, W6T, AH, Zg, Zg6, I, BS);
      seq_block<<<dim3(nr / BT), dim3(64), 0, stream>>>(
          WsT, W1T, W6bT, AH, Zg, Zg6, s_ws, u, outp, I, BS, c0);
    }
  }
}

// Round 12
// 1649.030 us; speedup vs baseline: 1.0275x; 1.0275x over previous
//
#include <hip/hip_runtime.h>

// Autoregressive masked net sampler.
//  - output col i == sampling-time x[:,i]  (masks: out i depends on spins < i only)
//  - spin blocks of KB=8: history part = dense GEMM (MFMA f16), intra-block part
//    sequential per-row (rows independent -> no grid sync).
// R9: split kernels (hist | seq), 1154us verified, SINGLE chunk (15552 B/row).
// R10-R13: fusion abandoned (compiler caps 8-wave WGs at 60-64 VGPR).
// R14: hist K-split x2 confirmed; seq t-roll refuted (unroll = the latency-hider).
// R15: R9 seq + f32 K-split partials: 18176 B/row OVERFLOWED ws -> batch chunked
//      (BS~12800, 32 launches, Zg un-L2-fit) -> seq 83us of exposed Zg traffic.
// R16 (this): K-split kept, partials stored F16 (2x1280 B/row == R9's 2560 B),
//      s_ws packed to i8 (64 B/row) -> per-row 15552 EXACTLY == R9 -> single
//      chunk restored. Zg read/write traffic also halves. Zg6 partials stay f32.

#define NS   64          // spins
#define HC   20          // hidden channels per spin
#define HTOT 1280        // NS*HC
#define NB   16384       // batch
#define KB   8           // spins per block (8 blocks)
#define BT   16          // batch rows per seq workgroup (MFMA N-tile)

typedef _Float16 f16;
typedef _Float16 f16x2 __attribute__((ext_vector_type(2)));
typedef _Float16 f16x4 __attribute__((ext_vector_type(4)));
typedef _Float16 f16x8 __attribute__((ext_vector_type(8)));
typedef float f32x4 __attribute__((ext_vector_type(4)));
typedef unsigned int u32x4 __attribute__((ext_vector_type(4)));

static __device__ __forceinline__ float sigm(float z) {
  return __builtin_amdgcn_rcpf(1.0f + __expf(-z));
}

static __device__ __forceinline__ unsigned pk2(float a, float b) {
  f16x2 t;
  t[0] = (f16)a;
  t[1] = (f16)b;
  return __builtin_bit_cast(unsigned, t);
}

// ---------------------------------------------------------------------------
// prep: build masked f16 weights, pre-swizzled to MFMA A-fragment order.
// Fragment order: lane = quad*16 + row15, elems 8; col = ks*32 + quad*8 + e.
//  WpT [L][rt=row/16][ks=0..39][512]    row=j_o*20+ch_o, mask j_i<=j_o (hist A)
//  WsT [L][i][tile=ch/16][ks=0..4][512] cols rel to HC*(i&~7), ch padded ->32 (seq A)
//  W1T [i][tile][ks=0..1][512]          cols = spins, mask c<i (seq L1 A)
//  W6bT[m*8+t][512]                     16 tp rows x 32 k, mask t<=tp,k<20 (z6 A)
//  W6T [m][ks=0..39][512]               16 tp rows (8 real), mask j_i<=I+tp
// ---------------------------------------------------------------------------
__global__ __launch_bounds__(256) void prep(
    const float* __restrict__ W1, const float* __restrict__ W2,
    const float* __restrict__ W3, const float* __restrict__ W4,
    const float* __restrict__ W5, const float* __restrict__ W6,
    f16* __restrict__ WpT, f16* __restrict__ WsT, f16* __restrict__ W1T,
    f16* __restrict__ W6bT, f16* __restrict__ W6T) {
  __shared__ float row[HTOT];
  int bid = blockIdx.x;
  if (bid < 4 * HTOT) {
    int L = bid / HTOT, cp = bid % HTOT;
    int j_o = cp / HC, ch_o = cp % HC;
    const float* Wsrc = (L == 0) ? W2 : (L == 1) ? W3 : (L == 2) ? W4 : W5;
    const float* src = Wsrc + (size_t)(ch_o * NS + j_o) * HTOT;
    for (int k = threadIdx.x; k < HTOT; k += 256) row[k] = src[k];
    __syncthreads();
    // WpT: this source row is A-row cp -> rt = cp>>4, row15 = cp&15
    {
      int rt = cp >> 4, rl = cp & 15;
      f16* dwp = WpT + (size_t)(L * 80 + rt) * 40 * 512;
      for (int xp = threadIdx.x; xp < HTOT; xp += 256) {
        int j_i = xp / HC, ch_i = xp % HC;
        f16 v = (f16)((j_i <= j_o) ? row[ch_i * NS + j_i] : 0.0f);
        int ks = xp >> 5, q = (xp >> 3) & 3, e = xp & 7;
        dwp[ks * 512 + (q * 16 + rl) * 8 + e] = v;
      }
    }
    // WsT: A-row ch_o of spin j_o, cols relative to block base HC*(j_o&~7)
    {
      int base = HC * (j_o & ~7);
      int tile = ch_o >> 4, tl = ch_o & 15;
      f16* dws = WsT + (size_t)(((L * NS + j_o) * 2 + tile) * 5) * 512;
      for (int kr = threadIdx.x; kr < 160; kr += 256) {
        int xp = base + kr;
        int j_i = xp / HC, ch_i = xp % HC;
        f16 v = (f16)((j_i <= j_o) ? row[ch_i * NS + j_i] : 0.0f);
        int ks = kr >> 5, q = (kr >> 3) & 3, e = kr & 7;
        dws[ks * 512 + (q * 16 + tl) * 8 + e] = v;
      }
      if (ch_o < 12) {  // zero pad rows ch=20..31 (tile1 rows 4..15)
        int zl = (20 + ch_o) & 15;
        f16* dz = WsT + (size_t)(((L * NS + j_o) * 2 + 1) * 5) * 512;
        for (int kr = threadIdx.x; kr < 160; kr += 256) {
          int ks = kr >> 5, q = (kr >> 3) & 3, e = kr & 7;
          dz[ks * 512 + (q * 16 + zl) * 8 + e] = (f16)0.0f;
        }
      }
    }
  } else if (bid < 4 * HTOT + NS) {
    int j_o = bid - 4 * HTOT;
    for (int idx = threadIdx.x; idx < 32 * 64; idx += 256) {
      int ch = idx >> 6, c = idx & 63;
      float v = (ch < HC && c < j_o) ? W1[((size_t)ch * NS + j_o) * NS + c] : 0.0f;
      int tile = ch >> 4, tl = ch & 15, ks = c >> 5, q = (c >> 3) & 3, e = c & 7;
      W1T[(size_t)((j_o * 2 + tile) * 2 + ks) * 512 + (q * 16 + tl) * 8 + e] = (f16)v;
    }
  } else if (bid < 4 * HTOT + NS + 8) {
    int m = bid - (4 * HTOT + NS);
    int I = m * KB;
    for (int idx = threadIdx.x; idx < 8 * 16 * 32; idx += 256) {
      int t = idx >> 9, tp = (idx >> 5) & 15, k = idx & 31;
      float v = (tp < 8 && k < HC && t <= tp)
                    ? W6[(size_t)(I + tp) * HTOT + k * NS + (I + t)]
                    : 0.0f;
      int q = k >> 3, e = k & 7;
      W6bT[(size_t)(m * 8 + t) * 512 + (q * 16 + tp) * 8 + e] = (f16)v;
    }
  } else {
    int m = bid - (4 * HTOT + NS + 8);
    int I = m * KB;
    for (int idx = threadIdx.x; idx < 16 * HTOT; idx += 256) {
      int tp = idx / HTOT, xp = idx % HTOT;
      int j_i = xp / HC, ch_i = xp % HC;
      float v = (tp < 8 && j_i <= I + tp)
                    ? W6[(size_t)(I + tp) * HTOT + ch_i * NS + j_i]
                    : 0.0f;
      int ks = xp >> 5, q = (xp >> 3) & 3, e = xp & 7;
      W6T[(size_t)(m * 40 + ks) * 512 + (q * 16 + tp) * 8 + e] = (f16)v;
    }
  }
}

// ---------------------------------------------------------------------------
// gemm_hist: history GEMMs for block at spin I; K-split x2 via blockIdx.z.
//  L<4 : ZgH[z][L*160+c][b] (f16)  partial over ks in [ks0, ks0+kn)
//  L==4: Zg6[z][tp][b]      (f32)  same split for the layer-6 rows
// A loads coalesced from fragment-order WpT/W6T; AH is raw B-fragment layout.
// Grid (nr/64, 5, 2) x 256 thr -> 20 waves/CU. [R14: confirmed mechanism]
// f16 partial store: halves Zg write traffic AND keeps per-row ws == R9.
// ---------------------------------------------------------------------------
__global__ __launch_bounds__(256) void gemm_hist(
    const f16* __restrict__ WpT, const f16* __restrict__ W6T,
    const f16* __restrict__ AH, f16* __restrict__ ZgH,
    float* __restrict__ Zg6, int I, int BS) {
  const int L = blockIdx.y;
  const int z = blockIdx.z;
  const int tid = threadIdx.x;
  const int lane = tid & 63;
  const int w = tid >> 6;
  const int l15 = tid & 15;
  const int quad = lane >> 4;
  const int m = I >> 3;
  const int G32 = (HC * I) >> 5;
  const int H0 = G32 >> 1;
  const int ks0 = z ? H0 : 0;
  const int kn = z ? (G32 - H0) : H0;
  f16* ZgP = ZgH + (size_t)z * 640 * BS;
  float* Zg6P = Zg6 + (size_t)z * 16 * BS;

  if (L == 4) {
    const int b0 = blockIdx.x * 64 + w * 16;
    f32x4 acc = (f32x4){0.f, 0.f, 0.f, 0.f};
    const f16* ap = W6T + ((size_t)(m * 40) + ks0) * 512 + lane * 8;
    const f16* bp = AH + ((size_t)(4 * 160 + 4 * ks0 + quad) * BS + b0 + l15) * 8;
#pragma unroll 2
    for (int ks = 0; ks < kn; ++ks) {
      f16x8 af = *(const f16x8*)ap;
      f16x8 bf = *(const f16x8*)bp;
      acc = __builtin_amdgcn_mfma_f32_16x16x32_f16(af, bf, acc, 0, 0, 0);
      ap += 512;
      bp += (size_t)4 * BS * 8;
    }
#pragma unroll
    for (int r = 0; r < 4; ++r)
      Zg6P[(size_t)(quad * 4 + r) * BS + b0 + l15] = acc[r];
    return;
  }

  const int wm = w & 1, wn = w >> 1;
  const int b0 = blockIdx.x * 64 + wn * 32;

  f32x4 acc[5][2];
#pragma unroll
  for (int mt = 0; mt < 5; ++mt) {
    acc[mt][0] = (f32x4){0.f, 0.f, 0.f, 0.f};
    acc[mt][1] = (f32x4){0.f, 0.f, 0.f, 0.f};
  }

  const f16* ap =
      WpT + ((size_t)((L * 80 + 10 * m + 5 * wm) * 40) + ks0) * 512 + lane * 8;
  const f16* bp = AH + ((size_t)(L * 160 + 4 * ks0 + quad) * BS + b0 + l15) * 8;

#pragma unroll 2
  for (int ks = 0; ks < kn; ++ks) {
    f16x8 bf0 = *(const f16x8*)(bp);
    f16x8 bf1 = *(const f16x8*)(bp + 128);
    f16x8 af[5];
#pragma unroll
    for (int mt = 0; mt < 5; ++mt)
      af[mt] = *(const f16x8*)(ap + (size_t)mt * 40 * 512);
#pragma unroll
    for (int mt = 0; mt < 5; ++mt) {
      acc[mt][0] = __builtin_amdgcn_mfma_f32_16x16x32_f16(af[mt], bf0, acc[mt][0], 0, 0, 0);
      acc[mt][1] = __builtin_amdgcn_mfma_f32_16x16x32_f16(af[mt], bf1, acc[mt][1], 0, 0, 0);
    }
    ap += 512;
    bp += (size_t)4 * BS * 8;
  }

#pragma unroll
  for (int mt = 0; mt < 5; ++mt)
#pragma unroll
    for (int nt = 0; nt < 2; ++nt)
#pragma unroll
      for (int r = 0; r < 4; ++r) {
        int c = wm * 80 + mt * 16 + quad * 4 + r;
        int b = b0 + nt * 16 + l15;
        ZgP[(size_t)(L * 160 + c) * BS + b] = (f16)acc[mt][nt][r];
      }
}

// ---------------------------------------------------------------------------
// seq_block v7 (R9 structure, latency-pipelined MFMA phases): 1 wave, BT=16.
// Full t-unroll (cross-t load hoisting is the latency-hiding mechanism — R14
// proved rolling this loop costs +70%); Zg post-added as SUM OF TWO F16 K-SPLIT
// PARTIALS (halved traffic vs R9's f32); u preloaded; z6 via shfl from layer-5
// C-regs; sampled bit carried in reg and patched into next t's L1 B-frag;
// global sampled-bit store s_ws packed to i8.
// ---------------------------------------------------------------------------
__global__ __launch_bounds__(64) void seq_block(
    const f16* __restrict__ WsT, const f16* __restrict__ W1T,
    const f16* __restrict__ W6bT, f16* __restrict__ AH,
    const f16* __restrict__ ZgH, const float* __restrict__ Zg6,
    signed char* __restrict__ s_ws, const float* __restrict__ u,
    float* __restrict__ outp, int I, int BS, int b0) {
  __shared__ __align__(16) f16 aL[5][BT][184];   // 29440 B
  __shared__ __align__(16) f16 sL[BT][72];       // 2304 B -> 31744 B total

  const int lane = threadIdx.x;
  const int l15 = lane & 15;            // MFMA col = batch row in WG
  const int quad = lane >> 4;           // MFMA k-group / C row-group
  const int m = I >> 3;
  const int bcol = blockIdx.x * BT + l15;
  const int bg = b0 + bcol;
  const size_t ZHN = (size_t)640 * BS;    // f16 K-split partial stride
  const size_t Zg6PN = (size_t)16 * BS;

  // early global loads: u for all 8 spins, z6 accumulator init (sum partials)
  float uv[KB];
#pragma unroll
  for (int t = 0; t < KB; ++t) uv[t] = u[(size_t)(I + t) * NB + bg];
  f32x4 acc6;
#pragma unroll
  for (int r = 0; r < 4; ++r) {
    size_t o = (size_t)(quad * 4 + r) * BS + bcol;
    acc6[r] = Zg6[o] + Zg6[Zg6PN + o];
  }

  // zero LDS (masked-weight / K-pad tails must read as 0)
  {
    f16x8 z = {};
    f16x8* pa = (f16x8*)&aL[0][0][0];
    for (int k = lane; k < (5 * BT * 184) / 8; k += 64) pa[k] = z;
    f16x8* ps = (f16x8*)&sL[0][0];
    for (int k = lane; k < (BT * 72) / 8; k += 64) ps[k] = z;
  }
  __syncthreads();

  // load sampled-bit history j < I (i8 -> f16)
  for (int c8 = quad; c8 < (I >> 3); c8 += 4) {
    unsigned long long raw = *(const unsigned long long*)(
        s_ws + (size_t)(blockIdx.x * BT + l15) * NS + c8 * 8);
    f16x8 v;
#pragma unroll
    for (int e = 0; e < 8; ++e) {
      signed char c = (signed char)(raw >> (8 * e));
      v[e] = (f16)(float)c;
    }
    *(f16x8*)&sL[l15][c8 * 8] = v;
  }
  __syncthreads();

  float bitv = 0.0f;  // freshest sampled bit (spin I+t-1), per batch-column

#pragma unroll
  for (int t = 0; t < KB; ++t) {
    const int i = I + t;

    // ---- prefetch this t's Zg rows (sum of 2 f16 partials), all 4 layers ----
    float zg0[4][4], zg1[4][4];
#pragma unroll
    for (int L = 0; L < 4; ++L)
#pragma unroll
      for (int r = 0; r < 4; ++r) {
        size_t o0 = (size_t)(L * 160 + t * HC + quad * 4 + r) * BS + bcol;
        zg0[L][r] = (float)ZgH[o0] + (float)ZgH[ZHN + o0];
        size_t o1 = (size_t)(L * 160 + t * HC + 16 + r) * BS + bcol;
        zg1[L][r] = (quad == 0) ? ((float)ZgH[o1] + (float)ZgH[ZHN + o1]) : 0.f;
      }

    // ---- layer 1: z[32ch x 16b] = W1(i) (32x64) . sL (64x16) ----
    {
      f32x4 z0 = (f32x4){0.f, 0.f, 0.f, 0.f};
      f32x4 z1 = (f32x4){0.f, 0.f, 0.f, 0.f};
      const int KS1 = (i + 31) >> 5;
      const f16* w0 = W1T + (size_t)(i * 2) * 2 * 512 + lane * 8;
      for (int ks = 0; ks < KS1; ++ks) {
        f16x8 bf = *(const f16x8*)&sL[l15][quad * 8 + 32 * ks];
        if (t > 0 && ks == ((i - 1) >> 5) && quad == (((I & 31) + t - 1) >> 3))
          bf[(t - 1) & 7] = (f16)bitv;  // freshest bit, not yet LDS-visible
        f16x8 a0 = *(const f16x8*)(w0 + ks * 512);
        f16x8 a1 = *(const f16x8*)(w0 + (2 + ks) * 512);
        z0 = __builtin_amdgcn_mfma_f32_16x16x32_f16(a0, bf, z0, 0, 0, 0);
        z1 = __builtin_amdgcn_mfma_f32_16x16x32_f16(a1, bf, z1, 0, 0, 0);
      }
      f16x4 o0;
#pragma unroll
      for (int r = 0; r < 4; ++r) o0[r] = (f16)sigm(z0[r]);
      *(f16x4*)&aL[0][l15][t * HC + quad * 4] = o0;
      if (quad == 0) {
        f16x4 o1;
#pragma unroll
        for (int r = 0; r < 4; ++r) o1[r] = (f16)sigm(z1[r]);
        *(f16x4*)&aL[0][l15][t * HC + 16] = o1;
      }
    }
    __syncthreads();

    // ---- layers 2..5: z = W(L,i) (32xK) . aL[L] (Kx16), then += Zg ----
    const int KS = (HC * (t + 1) + 31) >> 5;  // compile-time under unroll
    float a5o0[4], a5o1[4];
#pragma unroll
    for (int L = 0; L < 4; ++L) {
      f32x4 z0 = (f32x4){0.f, 0.f, 0.f, 0.f};
      f32x4 z1 = (f32x4){0.f, 0.f, 0.f, 0.f};
      const f16* wb = WsT + (size_t)((L * NS + i) * 2) * 5 * 512 + lane * 8;
#pragma unroll
      for (int ks = 0; ks < KS; ++ks) {
        f16x8 bf = *(const f16x8*)&aL[L][l15][quad * 8 + 32 * ks];
        f16x8 a0 = *(const f16x8*)(wb + ks * 512);
        f16x8 a1 = *(const f16x8*)(wb + (5 + ks) * 512);
        z0 = __builtin_amdgcn_mfma_f32_16x16x32_f16(a0, bf, z0, 0, 0, 0);
        z1 = __builtin_amdgcn_mfma_f32_16x16x32_f16(a1, bf, z1, 0, 0, 0);
      }
      f16x4 o0;
#pragma unroll
      for (int r = 0; r < 4; ++r) {
        float v = sigm(z0[r] + zg0[L][r]);
        o0[r] = (f16)v;
        if (L == 3) a5o0[r] = v;
      }
      *(f16x4*)&aL[L + 1][l15][t * HC + quad * 4] = o0;
      {
        f16x4 o1;
#pragma unroll
        for (int r = 0; r < 4; ++r) {
          float v = sigm(z1[r] + zg1[L][r]);
          o1[r] = (f16)v;
          if (L == 3) a5o1[r] = v;
        }
        if (quad == 0) *(f16x4*)&aL[L + 1][l15][t * HC + 16] = o1;
      }
      if (L < 3) __syncthreads();  // aL[4] never cross-read before writeout
    }

    // ---- z6: B-frag = fresh a5 only (W6bT zero-masks k>=20) via shfl ----
    {
      unsigned p0 = pk2(a5o0[0], a5o0[1]);
      unsigned p1 = pk2(a5o0[2], a5o0[3]);
      unsigned p2 = pk2(a5o1[0], a5o1[1]);
      unsigned p3 = pk2(a5o1[2], a5o1[3]);
      int src1 = (((quad * 2) & 3) << 4) + l15;
      int src2 = src1 + 16;
      unsigned d0 = (unsigned)__shfl((int)p0, src1, 64);
      unsigned d1 = (unsigned)__shfl((int)p1, src1, 64);
      unsigned d2 = (unsigned)__shfl((int)p0, src2, 64);
      unsigned d3 = (unsigned)__shfl((int)p1, src2, 64);
      unsigned e0 = (unsigned)__shfl((int)p2, src1, 64);
      unsigned e1 = (unsigned)__shfl((int)p3, src1, 64);
      u32x4 bv = (quad < 2) ? (u32x4){d0, d1, d2, d3} : (u32x4){e0, e1, e0, e1};
      f16x8 b5 = __builtin_bit_cast(f16x8, bv);
      f16x8 a6 = *(const f16x8*)(W6bT + (size_t)(m * 8 + t) * 512 + lane * 8);
      acc6 = __builtin_amdgcn_mfma_f32_16x16x32_f16(a6, b5, acc6, 0, 0, 0);
      // extract row t (owner quad = t>>2, reg t&3; static under unroll)
      float x = sigm(acc6[t & 3]);
      if (quad == (t >> 2)) {
        outp[(size_t)bg * NS + i] = x;  // final output col i == sampling-time x
        sL[l15][i] = (f16)((x >= uv[t]) ? 1.0f : -1.0f);
      }
      float xall = __shfl(x, ((t >> 2) << 4) + l15, 64);
      bitv = (xall >= uv[t]) ? 1.0f : -1.0f;
    }
    // no end-of-t barrier: t+1 L1 gets the fresh bit from bitv; older sL writes
    // are >= 4 syncs old; aL[4] writes only read after the final barrier.
  }
  __syncthreads();

  // ---- bulk writeout: block activations -> global AH ([L][g][b][e]), s bits ----
  for (int w = lane; w < 5 * 20 * BT; w += 64) {
    int rr = w & 15;
    int q = w >> 4;            // 0..99
    int L = q / 20, x8 = q % 20;
    f16x8 v = *(const f16x8*)&aL[L][rr][x8 * 8];
    int gg = ((HC * I) >> 3) + x8;
    *(f16x8*)(AH + ((size_t)(L * 160 + gg) * BS + blockIdx.x * BT + rr) * 8) = v;
  }
  if (lane < BT) {
    unsigned long long pk = 0;
#pragma unroll
    for (int e = 0; e < 8; ++e) {
      float f = (float)sL[lane][I + e];
      unsigned char c = (unsigned char)(signed char)((f >= 0.f) ? 1 : -1);
      pk |= (unsigned long long)c << (8 * e);
    }
    *(unsigned long long*)(s_ws + (size_t)(blockIdx.x * BT + lane) * NS + I) = pk;
  }
}

// ---------------------------------------------------------------------------
extern "C" void kernel_launch(void* const* d_in, const int* in_sizes, int n_in,
                              void* d_out, int out_size, void* d_ws, size_t ws_size,
                              hipStream_t stream) {
  (void)in_sizes; (void)n_in; (void)out_size;
  const float* u  = (const float*)d_in[1];
  const float* W1 = (const float*)d_in[2];
  const float* W2 = (const float*)d_in[3];
  const float* W3 = (const float*)d_in[4];
  const float* W4 = (const float*)d_in[5];
  const float* W5 = (const float*)d_in[6];
  const float* W6 = (const float*)d_in[7];
  float* outp = (float*)d_out;

  const size_t wpTEls  = (size_t)4 * 80 * 40 * 512;      // 6.55M  hist A
  const size_t wsTEls  = (size_t)4 * NS * 2 * 5 * 512;   // 1.31M  seq A
  const size_t w1TEls  = (size_t)NS * 2 * 2 * 512;       // 131K   seq L1 A
  const size_t w6bTEls = (size_t)64 * 512;               // 33K    seq z6 A
  const size_t w6TEls  = (size_t)8 * 40 * 512;           // 164K   hist z6 A
  const size_t wEls = wpTEls + wsTEls + w1TEls + w6bTEls + w6TEls;
  const size_t wBytes = wEls * sizeof(f16);

  // per-row: AH 12800 + ZgH 2x1280(f16) + Zg6 2x64(f32) + s_ws 64(i8) = 15552 B
  // == R9's proven single-chunk footprint.
  size_t rem = (ws_size > wBytes + 4096) ? (ws_size - wBytes - 4096) : 0;
  long long bs = (long long)(rem / 15552);
  bs = (bs / 64) * 64;
  if (bs > NB) bs = NB;
  if (bs < 64) bs = 64;
  const int BS = (int)bs;

  f16* WpT   = (f16*)d_ws;
  f16* WsT   = WpT + wpTEls;
  f16* W1T   = WsT + wsTEls;
  f16* W6bT  = W1T + w1TEls;
  f16* W6T   = W6bT + w6bTEls;
  f16* AH    = W6T + w6TEls;
  f16* ZgH   = AH + (size_t)5 * 160 * BS * 8;
  float* Zg6 = (float*)(ZgH + (size_t)2 * 640 * BS);
  signed char* s_ws = (signed char*)(Zg6 + (size_t)2 * 16 * BS);

  prep<<<dim3(4 * HTOT + NS + 16), dim3(256), 0, stream>>>(
      W1, W2, W3, W4, W5, W6, WpT, WsT, W1T, W6bT, W6T);

  for (int c0 = 0; c0 < NB; c0 += BS) {
    int nr = NB - c0; if (nr > BS) nr = BS;
    for (int m = 0; m < NS / KB; ++m) {
      const int I = m * KB;
      gemm_hist<<<dim3(nr / 64, 5, 2), dim3(256), 0, stream>>>(
          WpT, W6T, AH, ZgH, Zg6, I, BS);
      seq_block<<<dim3(nr / BT), dim3(64), 0, stream>>>(
          WsT, W1T, W6bT, AH, ZgH, Zg6, s_ws, u, outp, I, BS, c0);
    }
  }
}

// Round 13
// 1638.794 us; speedup vs baseline: 1.0339x; 1.0062x over previous
//
#include <hip/hip_runtime.h>

// Autoregressive masked net sampler.
//  - output col i == sampling-time x[:,i]  (masks: out i depends on spins < i only)
//  - spin blocks of KB=8: history part = dense GEMM (MFMA f16), intra-block part
//    sequential per-row (rows independent -> no grid sync).
// R9: split kernels (hist | seq), 1154us verified (15552 B/row, single chunk).
// R10-R13: fusion abandoned (compiler caps 8-wave WGs at 60-64 VGPR).
// R14: hist K-split x2 confirmed; seq t-roll refuted (unroll = the latency-hider).
// R15/R16: K-split partials regressed seq (73-85MB FETCH vs 42MB volume):
//      separate partial buffers -> each WG consumes 32B of every 64B line and
//      the 2nd partial doubles the line count -> 2x HBM amplification on the
//      zero-TLP chain. (R15 chunking theory retracted; f16 precision confirmed.)
// R17 (this): INTERLEAVE partials: ZgH[row][2*b+z]. Seq loads ONE u32 per (L,r)
//      (same addresses as R9's f32 loads, full-line consumption, both partials
//      per load); hist z=0/z=1 write complementary line-halves concurrently.

#define NS   64          // spins
#define HC   20          // hidden channels per spin
#define HTOT 1280        // NS*HC
#define NB   16384       // batch
#define KB   8           // spins per block (8 blocks)
#define BT   16          // batch rows per seq workgroup (MFMA N-tile)

typedef _Float16 f16;
typedef _Float16 f16x2 __attribute__((ext_vector_type(2)));
typedef _Float16 f16x4 __attribute__((ext_vector_type(4)));
typedef _Float16 f16x8 __attribute__((ext_vector_type(8)));
typedef float f32x4 __attribute__((ext_vector_type(4)));
typedef unsigned int u32x4 __attribute__((ext_vector_type(4)));

static __device__ __forceinline__ float sigm(float z) {
  return __builtin_amdgcn_rcpf(1.0f + __expf(-z));
}

static __device__ __forceinline__ unsigned pk2(float a, float b) {
  f16x2 t;
  t[0] = (f16)a;
  t[1] = (f16)b;
  return __builtin_bit_cast(unsigned, t);
}

// ---------------------------------------------------------------------------
// prep: build masked f16 weights, pre-swizzled to MFMA A-fragment order.
// Fragment order: lane = quad*16 + row15, elems 8; col = ks*32 + quad*8 + e.
//  WpT [L][rt=row/16][ks=0..39][512]    row=j_o*20+ch_o, mask j_i<=j_o (hist A)
//  WsT [L][i][tile=ch/16][ks=0..4][512] cols rel to HC*(i&~7), ch padded ->32 (seq A)
//  W1T [i][tile][ks=0..1][512]          cols = spins, mask c<i (seq L1 A)
//  W6bT[m*8+t][512]                     16 tp rows x 32 k, mask t<=tp,k<20 (z6 A)
//  W6T [m][ks=0..39][512]               16 tp rows (8 real), mask j_i<=I+tp
// ---------------------------------------------------------------------------
__global__ __launch_bounds__(256) void prep(
    const float* __restrict__ W1, const float* __restrict__ W2,
    const float* __restrict__ W3, const float* __restrict__ W4,
    const float* __restrict__ W5, const float* __restrict__ W6,
    f16* __restrict__ WpT, f16* __restrict__ WsT, f16* __restrict__ W1T,
    f16* __restrict__ W6bT, f16* __restrict__ W6T) {
  __shared__ float row[HTOT];
  int bid = blockIdx.x;
  if (bid < 4 * HTOT) {
    int L = bid / HTOT, cp = bid % HTOT;
    int j_o = cp / HC, ch_o = cp % HC;
    const float* Wsrc = (L == 0) ? W2 : (L == 1) ? W3 : (L == 2) ? W4 : W5;
    const float* src = Wsrc + (size_t)(ch_o * NS + j_o) * HTOT;
    for (int k = threadIdx.x; k < HTOT; k += 256) row[k] = src[k];
    __syncthreads();
    // WpT: this source row is A-row cp -> rt = cp>>4, row15 = cp&15
    {
      int rt = cp >> 4, rl = cp & 15;
      f16* dwp = WpT + (size_t)(L * 80 + rt) * 40 * 512;
      for (int xp = threadIdx.x; xp < HTOT; xp += 256) {
        int j_i = xp / HC, ch_i = xp % HC;
        f16 v = (f16)((j_i <= j_o) ? row[ch_i * NS + j_i] : 0.0f);
        int ks = xp >> 5, q = (xp >> 3) & 3, e = xp & 7;
        dwp[ks * 512 + (q * 16 + rl) * 8 + e] = v;
      }
    }
    // WsT: A-row ch_o of spin j_o, cols relative to block base HC*(j_o&~7)
    {
      int base = HC * (j_o & ~7);
      int tile = ch_o >> 4, tl = ch_o & 15;
      f16* dws = WsT + (size_t)(((L * NS + j_o) * 2 + tile) * 5) * 512;
      for (int kr = threadIdx.x; kr < 160; kr += 256) {
        int xp = base + kr;
        int j_i = xp / HC, ch_i = xp % HC;
        f16 v = (f16)((j_i <= j_o) ? row[ch_i * NS + j_i] : 0.0f);
        int ks = kr >> 5, q = (kr >> 3) & 3, e = kr & 7;
        dws[ks * 512 + (q * 16 + tl) * 8 + e] = v;
      }
      if (ch_o < 12) {  // zero pad rows ch=20..31 (tile1 rows 4..15)
        int zl = (20 + ch_o) & 15;
        f16* dz = WsT + (size_t)(((L * NS + j_o) * 2 + 1) * 5) * 512;
        for (int kr = threadIdx.x; kr < 160; kr += 256) {
          int ks = kr >> 5, q = (kr >> 3) & 3, e = kr & 7;
          dz[ks * 512 + (q * 16 + zl) * 8 + e] = (f16)0.0f;
        }
      }
    }
  } else if (bid < 4 * HTOT + NS) {
    int j_o = bid - 4 * HTOT;
    for (int idx = threadIdx.x; idx < 32 * 64; idx += 256) {
      int ch = idx >> 6, c = idx & 63;
      float v = (ch < HC && c < j_o) ? W1[((size_t)ch * NS + j_o) * NS + c] : 0.0f;
      int tile = ch >> 4, tl = ch & 15, ks = c >> 5, q = (c >> 3) & 3, e = c & 7;
      W1T[(size_t)((j_o * 2 + tile) * 2 + ks) * 512 + (q * 16 + tl) * 8 + e] = (f16)v;
    }
  } else if (bid < 4 * HTOT + NS + 8) {
    int m = bid - (4 * HTOT + NS);
    int I = m * KB;
    for (int idx = threadIdx.x; idx < 8 * 16 * 32; idx += 256) {
      int t = idx >> 9, tp = (idx >> 5) & 15, k = idx & 31;
      float v = (tp < 8 && k < HC && t <= tp)
                    ? W6[(size_t)(I + tp) * HTOT + k * NS + (I + t)]
                    : 0.0f;
      int q = k >> 3, e = k & 7;
      W6bT[(size_t)(m * 8 + t) * 512 + (q * 16 + tp) * 8 + e] = (f16)v;
    }
  } else {
    int m = bid - (4 * HTOT + NS + 8);
    int I = m * KB;
    for (int idx = threadIdx.x; idx < 16 * HTOT; idx += 256) {
      int tp = idx / HTOT, xp = idx % HTOT;
      int j_i = xp / HC, ch_i = xp % HC;
      float v = (tp < 8 && j_i <= I + tp)
                    ? W6[(size_t)(I + tp) * HTOT + ch_i * NS + j_i]
                    : 0.0f;
      int ks = xp >> 5, q = (xp >> 3) & 3, e = xp & 7;
      W6T[(size_t)(m * 40 + ks) * 512 + (q * 16 + tp) * 8 + e] = (f16)v;
    }
  }
}

// ---------------------------------------------------------------------------
// gemm_hist: history GEMMs for block at spin I; K-split x2 via blockIdx.z.
//  L<4 : ZgH[(L*160+c)][2*b + z] (f16, interleaved partials)
//  L==4: Zg6[z][tp][b]           (f32, separate partials — tiny)
// A loads coalesced from fragment-order WpT/W6T; AH is raw B-fragment layout.
// Grid (nr/64, 5, 2) x 256 thr -> 20 waves/CU. [R14: confirmed mechanism]
// Interleaved store: z=0/z=1 blocks write complementary halves of each 64B
// line concurrently -> L2 merges; seq reads both partials in ONE u32 load.
// ---------------------------------------------------------------------------
__global__ __launch_bounds__(256) void gemm_hist(
    const f16* __restrict__ WpT, const f16* __restrict__ W6T,
    const f16* __restrict__ AH, f16* __restrict__ ZgH,
    float* __restrict__ Zg6, int I, int BS) {
  const int L = blockIdx.y;
  const int z = blockIdx.z;
  const int tid = threadIdx.x;
  const int lane = tid & 63;
  const int w = tid >> 6;
  const int l15 = tid & 15;
  const int quad = lane >> 4;
  const int m = I >> 3;
  const int G32 = (HC * I) >> 5;
  const int H0 = G32 >> 1;
  const int ks0 = z ? H0 : 0;
  const int kn = z ? (G32 - H0) : H0;
  float* Zg6P = Zg6 + (size_t)z * 16 * BS;

  if (L == 4) {
    const int b0 = blockIdx.x * 64 + w * 16;
    f32x4 acc = (f32x4){0.f, 0.f, 0.f, 0.f};
    const f16* ap = W6T + ((size_t)(m * 40) + ks0) * 512 + lane * 8;
    const f16* bp = AH + ((size_t)(4 * 160 + 4 * ks0 + quad) * BS + b0 + l15) * 8;
#pragma unroll 2
    for (int ks = 0; ks < kn; ++ks) {
      f16x8 af = *(const f16x8*)ap;
      f16x8 bf = *(const f16x8*)bp;
      acc = __builtin_amdgcn_mfma_f32_16x16x32_f16(af, bf, acc, 0, 0, 0);
      ap += 512;
      bp += (size_t)4 * BS * 8;
    }
#pragma unroll
    for (int r = 0; r < 4; ++r)
      Zg6P[(size_t)(quad * 4 + r) * BS + b0 + l15] = acc[r];
    return;
  }

  const int wm = w & 1, wn = w >> 1;
  const int b0 = blockIdx.x * 64 + wn * 32;

  f32x4 acc[5][2];
#pragma unroll
  for (int mt = 0; mt < 5; ++mt) {
    acc[mt][0] = (f32x4){0.f, 0.f, 0.f, 0.f};
    acc[mt][1] = (f32x4){0.f, 0.f, 0.f, 0.f};
  }

  const f16* ap =
      WpT + ((size_t)((L * 80 + 10 * m + 5 * wm) * 40) + ks0) * 512 + lane * 8;
  const f16* bp = AH + ((size_t)(L * 160 + 4 * ks0 + quad) * BS + b0 + l15) * 8;

#pragma unroll 2
  for (int ks = 0; ks < kn; ++ks) {
    f16x8 bf0 = *(const f16x8*)(bp);
    f16x8 bf1 = *(const f16x8*)(bp + 128);
    f16x8 af[5];
#pragma unroll
    for (int mt = 0; mt < 5; ++mt)
      af[mt] = *(const f16x8*)(ap + (size_t)mt * 40 * 512);
#pragma unroll
    for (int mt = 0; mt < 5; ++mt) {
      acc[mt][0] = __builtin_amdgcn_mfma_f32_16x16x32_f16(af[mt], bf0, acc[mt][0], 0, 0, 0);
      acc[mt][1] = __builtin_amdgcn_mfma_f32_16x16x32_f16(af[mt], bf1, acc[mt][1], 0, 0, 0);
    }
    ap += 512;
    bp += (size_t)4 * BS * 8;
  }

#pragma unroll
  for (int mt = 0; mt < 5; ++mt)
#pragma unroll
    for (int nt = 0; nt < 2; ++nt)
#pragma unroll
      for (int r = 0; r < 4; ++r) {
        int c = wm * 80 + mt * 16 + quad * 4 + r;
        int b = b0 + nt * 16 + l15;
        ZgH[(size_t)(L * 160 + c) * 2 * BS + 2 * b + z] = (f16)acc[mt][nt][r];
      }
}

// ---------------------------------------------------------------------------
// seq_block v7 (R9 structure, latency-pipelined MFMA phases): 1 wave, BT=16.
// Full t-unroll (cross-t load hoisting is the latency-hiding mechanism — R14
// proved rolling this loop costs +70%); Zg post-added from INTERLEAVED f16
// partials: one u32 load per (L,r) yields both partials (same addresses as
// R9's f32 loads, full 64B-line consumption); u preloaded; z6 via shfl from
// layer-5 C-regs; sampled bit carried in reg; s_ws packed i8.
// ---------------------------------------------------------------------------
__global__ __launch_bounds__(64) void seq_block(
    const f16* __restrict__ WsT, const f16* __restrict__ W1T,
    const f16* __restrict__ W6bT, f16* __restrict__ AH,
    const f16* __restrict__ ZgH, const float* __restrict__ Zg6,
    signed char* __restrict__ s_ws, const float* __restrict__ u,
    float* __restrict__ outp, int I, int BS, int b0) {
  __shared__ __align__(16) f16 aL[5][BT][184];   // 29440 B
  __shared__ __align__(16) f16 sL[BT][72];       // 2304 B -> 31744 B total

  const int lane = threadIdx.x;
  const int l15 = lane & 15;            // MFMA col = batch row in WG
  const int quad = lane >> 4;           // MFMA k-group / C row-group
  const int m = I >> 3;
  const int bcol = blockIdx.x * BT + l15;
  const int bg = b0 + bcol;
  const unsigned* Zp = (const unsigned*)ZgH;  // u32 view: [row][b] like R9 f32
  const size_t Zg6PN = (size_t)16 * BS;

  // early global loads: u for all 8 spins, z6 accumulator init (sum partials)
  float uv[KB];
#pragma unroll
  for (int t = 0; t < KB; ++t) uv[t] = u[(size_t)(I + t) * NB + bg];
  f32x4 acc6;
#pragma unroll
  for (int r = 0; r < 4; ++r) {
    size_t o = (size_t)(quad * 4 + r) * BS + bcol;
    acc6[r] = Zg6[o] + Zg6[Zg6PN + o];
  }

  // zero LDS (masked-weight / K-pad tails must read as 0)
  {
    f16x8 z = {};
    f16x8* pa = (f16x8*)&aL[0][0][0];
    for (int k = lane; k < (5 * BT * 184) / 8; k += 64) pa[k] = z;
    f16x8* ps = (f16x8*)&sL[0][0];
    for (int k = lane; k < (BT * 72) / 8; k += 64) ps[k] = z;
  }
  __syncthreads();

  // load sampled-bit history j < I (i8 -> f16)
  for (int c8 = quad; c8 < (I >> 3); c8 += 4) {
    unsigned long long raw = *(const unsigned long long*)(
        s_ws + (size_t)(blockIdx.x * BT + l15) * NS + c8 * 8);
    f16x8 v;
#pragma unroll
    for (int e = 0; e < 8; ++e) {
      signed char c = (signed char)(raw >> (8 * e));
      v[e] = (f16)(float)c;
    }
    *(f16x8*)&sL[l15][c8 * 8] = v;
  }
  __syncthreads();

  float bitv = 0.0f;  // freshest sampled bit (spin I+t-1), per batch-column

#pragma unroll
  for (int t = 0; t < KB; ++t) {
    const int i = I + t;

    // ---- prefetch this t's Zg rows (1 u32 = both partials), all 4 layers ----
    float zg0[4][4], zg1[4][4];
#pragma unroll
    for (int L = 0; L < 4; ++L)
#pragma unroll
      for (int r = 0; r < 4; ++r) {
        unsigned v0 = Zp[(size_t)(L * 160 + t * HC + quad * 4 + r) * BS + bcol];
        f16x2 p0 = __builtin_bit_cast(f16x2, v0);
        zg0[L][r] = (float)p0[0] + (float)p0[1];
        if (quad == 0) {
          unsigned v1 = Zp[(size_t)(L * 160 + t * HC + 16 + r) * BS + bcol];
          f16x2 p1 = __builtin_bit_cast(f16x2, v1);
          zg1[L][r] = (float)p1[0] + (float)p1[1];
        } else {
          zg1[L][r] = 0.f;
        }
      }

    // ---- layer 1: z[32ch x 16b] = W1(i) (32x64) . sL (64x16) ----
    {
      f32x4 z0 = (f32x4){0.f, 0.f, 0.f, 0.f};
      f32x4 z1 = (f32x4){0.f, 0.f, 0.f, 0.f};
      const int KS1 = (i + 31) >> 5;
      const f16* w0 = W1T + (size_t)(i * 2) * 2 * 512 + lane * 8;
      for (int ks = 0; ks < KS1; ++ks) {
        f16x8 bf = *(const f16x8*)&sL[l15][quad * 8 + 32 * ks];
        if (t > 0 && ks == ((i - 1) >> 5) && quad == (((I & 31) + t - 1) >> 3))
          bf[(t - 1) & 7] = (f16)bitv;  // freshest bit, not yet LDS-visible
        f16x8 a0 = *(const f16x8*)(w0 + ks * 512);
        f16x8 a1 = *(const f16x8*)(w0 + (2 + ks) * 512);
        z0 = __builtin_amdgcn_mfma_f32_16x16x32_f16(a0, bf, z0, 0, 0, 0);
        z1 = __builtin_amdgcn_mfma_f32_16x16x32_f16(a1, bf, z1, 0, 0, 0);
      }
      f16x4 o0;
#pragma unroll
      for (int r = 0; r < 4; ++r) o0[r] = (f16)sigm(z0[r]);
      *(f16x4*)&aL[0][l15][t * HC + quad * 4] = o0;
      if (quad == 0) {
        f16x4 o1;
#pragma unroll
        for (int r = 0; r < 4; ++r) o1[r] = (f16)sigm(z1[r]);
        *(f16x4*)&aL[0][l15][t * HC + 16] = o1;
      }
    }
    __syncthreads();

    // ---- layers 2..5: z = W(L,i) (32xK) . aL[L] (Kx16), then += Zg ----
    const int KS = (HC * (t + 1) + 31) >> 5;  // compile-time under unroll
    float a5o0[4], a5o1[4];
#pragma unroll
    for (int L = 0; L < 4; ++L) {
      f32x4 z0 = (f32x4){0.f, 0.f, 0.f, 0.f};
      f32x4 z1 = (f32x4){0.f, 0.f, 0.f, 0.f};
      const f16* wb = WsT + (size_t)((L * NS + i) * 2) * 5 * 512 + lane * 8;
#pragma unroll
      for (int ks = 0; ks < KS; ++ks) {
        f16x8 bf = *(const f16x8*)&aL[L][l15][quad * 8 + 32 * ks];
        f16x8 a0 = *(const f16x8*)(wb + ks * 512);
        f16x8 a1 = *(const f16x8*)(wb + (5 + ks) * 512);
        z0 = __builtin_amdgcn_mfma_f32_16x16x32_f16(a0, bf, z0, 0, 0, 0);
        z1 = __builtin_amdgcn_mfma_f32_16x16x32_f16(a1, bf, z1, 0, 0, 0);
      }
      f16x4 o0;
#pragma unroll
      for (int r = 0; r < 4; ++r) {
        float v = sigm(z0[r] + zg0[L][r]);
        o0[r] = (f16)v;
        if (L == 3) a5o0[r] = v;
      }
      *(f16x4*)&aL[L + 1][l15][t * HC + quad * 4] = o0;
      {
        f16x4 o1;
#pragma unroll
        for (int r = 0; r < 4; ++r) {
          float v = sigm(z1[r] + zg1[L][r]);
          o1[r] = (f16)v;
          if (L == 3) a5o1[r] = v;
        }
        if (quad == 0) *(f16x4*)&aL[L + 1][l15][t * HC + 16] = o1;
      }
      if (L < 3) __syncthreads();  // aL[4] never cross-read before writeout
    }

    // ---- z6: B-frag = fresh a5 only (W6bT zero-masks k>=20) via shfl ----
    {
      unsigned p0 = pk2(a5o0[0], a5o0[1]);
      unsigned p1 = pk2(a5o0[2], a5o0[3]);
      unsigned p2 = pk2(a5o1[0], a5o1[1]);
      unsigned p3 = pk2(a5o1[2], a5o1[3]);
      int src1 = (((quad * 2) & 3) << 4) + l15;
      int src2 = src1 + 16;
      unsigned d0 = (unsigned)__shfl((int)p0, src1, 64);
      unsigned d1 = (unsigned)__shfl((int)p1, src1, 64);
      unsigned d2 = (unsigned)__shfl((int)p0, src2, 64);
      unsigned d3 = (unsigned)__shfl((int)p1, src2, 64);
      unsigned e0 = (unsigned)__shfl((int)p2, src1, 64);
      unsigned e1 = (unsigned)__shfl((int)p3, src1, 64);
      u32x4 bv = (quad < 2) ? (u32x4){d0, d1, d2, d3} : (u32x4){e0, e1, e0, e1};
      f16x8 b5 = __builtin_bit_cast(f16x8, bv);
      f16x8 a6 = *(const f16x8*)(W6bT + (size_t)(m * 8 + t) * 512 + lane * 8);
      acc6 = __builtin_amdgcn_mfma_f32_16x16x32_f16(a6, b5, acc6, 0, 0, 0);
      // extract row t (owner quad = t>>2, reg t&3; static under unroll)
      float x = sigm(acc6[t & 3]);
      if (quad == (t >> 2)) {
        outp[(size_t)bg * NS + i] = x;  // final output col i == sampling-time x
        sL[l15][i] = (f16)((x >= uv[t]) ? 1.0f : -1.0f);
      }
      float xall = __shfl(x, ((t >> 2) << 4) + l15, 64);
      bitv = (xall >= uv[t]) ? 1.0f : -1.0f;
    }
    // no end-of-t barrier: t+1 L1 gets the fresh bit from bitv; older sL writes
    // are >= 4 syncs old; aL[4] writes only read after the final barrier.
  }
  __syncthreads();

  // ---- bulk writeout: block activations -> global AH ([L][g][b][e]), s bits ----
  for (int w = lane; w < 5 * 20 * BT; w += 64) {
    int rr = w & 15;
    int q = w >> 4;            // 0..99
    int L = q / 20, x8 = q % 20;
    f16x8 v = *(const f16x8*)&aL[L][rr][x8 * 8];
    int gg = ((HC * I) >> 3) + x8;
    *(f16x8*)(AH + ((size_t)(L * 160 + gg) * BS + blockIdx.x * BT + rr) * 8) = v;
  }
  if (lane < BT) {
    unsigned long long pk = 0;
#pragma unroll
    for (int e = 0; e < 8; ++e) {
      float f = (float)sL[lane][I + e];
      unsigned char c = (unsigned char)(signed char)((f >= 0.f) ? 1 : -1);
      pk |= (unsigned long long)c << (8 * e);
    }
    *(unsigned long long*)(s_ws + (size_t)(blockIdx.x * BT + lane) * NS + I) = pk;
  }
}

// ---------------------------------------------------------------------------
extern "C" void kernel_launch(void* const* d_in, const int* in_sizes, int n_in,
                              void* d_out, int out_size, void* d_ws, size_t ws_size,
                              hipStream_t stream) {
  (void)in_sizes; (void)n_in; (void)out_size;
  const float* u  = (const float*)d_in[1];
  const float* W1 = (const float*)d_in[2];
  const float* W2 = (const float*)d_in[3];
  const float* W3 = (const float*)d_in[4];
  const float* W4 = (const float*)d_in[5];
  const float* W5 = (const float*)d_in[6];
  const float* W6 = (const float*)d_in[7];
  float* outp = (float*)d_out;

  const size_t wpTEls  = (size_t)4 * 80 * 40 * 512;      // 6.55M  hist A
  const size_t wsTEls  = (size_t)4 * NS * 2 * 5 * 512;   // 1.31M  seq A
  const size_t w1TEls  = (size_t)NS * 2 * 2 * 512;       // 131K   seq L1 A
  const size_t w6bTEls = (size_t)64 * 512;               // 33K    seq z6 A
  const size_t w6TEls  = (size_t)8 * 40 * 512;           // 164K   hist z6 A
  const size_t wEls = wpTEls + wsTEls + w1TEls + w6bTEls + w6TEls;
  const size_t wBytes = wEls * sizeof(f16);

  // per-row: AH 12800 + ZgH 640*2*2B + Zg6 2*16*4B + s_ws 64(i8) = 15552 B
  // == R9's proven single-chunk footprint.
  size_t rem = (ws_size > wBytes + 4096) ? (ws_size - wBytes - 4096) : 0;
  long long bs = (long long)(rem / 15552);
  bs = (bs / 64) * 64;
  if (bs > NB) bs = NB;
  if (bs < 64) bs = 64;
  const int BS = (int)bs;

  f16* WpT   = (f16*)d_ws;
  f16* WsT   = WpT + wpTEls;
  f16* W1T   = WsT + wsTEls;
  f16* W6bT  = W1T + w1TEls;
  f16* W6T   = W6bT + w6bTEls;
  f16* AH    = W6T + w6TEls;
  f16* ZgH   = AH + (size_t)5 * 160 * BS * 8;            // [640][2*BS] interleaved
  float* Zg6 = (float*)(ZgH + (size_t)640 * 2 * BS);
  signed char* s_ws = (signed char*)(Zg6 + (size_t)2 * 16 * BS);

  prep<<<dim3(4 * HTOT + NS + 16), dim3(256), 0, stream>>>(
      W1, W2, W3, W4, W5, W6, WpT, WsT, W1T, W6bT, W6T);

  for (int c0 = 0; c0 < NB; c0 += BS) {
    int nr = NB - c0; if (nr > BS) nr = BS;
    for (int m = 0; m < NS / KB; ++m) {
      const int I = m * KB;
      gemm_hist<<<dim3(nr / 64, 5, 2), dim3(256), 0, stream>>>(
          WpT, W6T, AH, ZgH, Zg6, I, BS);
      seq_block<<<dim3(nr / BT), dim3(64), 0, stream>>>(
          WsT, W1T, W6bT, AH, ZgH, Zg6, s_ws, u, outp, I, BS, c0);
    }
  }
}

// Round 14
// 925.938 us; speedup vs baseline: 1.8299x; 1.7699x over previous
//
#include <hip/hip_runtime.h>

// Autoregressive masked net sampler.
//  - output col i == sampling-time x[:,i]  (masks: out i depends on spins < i only)
//  - spin blocks of KB=8: history part = dense GEMM (MFMA f16), intra-block part
//    sequential per-row (rows independent -> no grid sync).
// R9: split kernels, 1154us. R10-R13: fusion abandoned (VGPR cap). R14: seq t-roll
//     refuted (unroll = the latency-hider). R15-R17: K-split partial layouts.
// R17 profile decoded the real cost model: seq dispatch duration (~55-80us) is a
//     WIDTH-INDEPENDENT latency chain; total seq = (#chunks x 8) x chain latency.
//     Per-row 15552B forced 2 chunks (14912+1472); the 1472-row tail's 8 seq
//     dispatches cost ~80us EACH doing almost nothing (FETCH 1.8MB, VALU 0.1%).
// R18 (this): force SINGLE chunk: per-row = AH 12800 + Zg f16 single (1280) +
//     Zg6 f32 (64) + s_ws i8 (64) = 14208B -> BS=16384 fits rem (~235MB).
//     Requires dropping hist K-split (2-partial buffer would re-force chunking;
//     its gain << chunk cost) -> hist = R9 unsplit form, f16 Zg writes. seq = R9
//     structure with single-buffer f16 Zg loads (f16 rounding validated R16/R17).

#define NS   64          // spins
#define HC   20          // hidden channels per spin
#define HTOT 1280        // NS*HC
#define NB   16384       // batch
#define KB   8           // spins per block (8 blocks)
#define BT   16          // batch rows per seq workgroup (MFMA N-tile)

typedef _Float16 f16;
typedef _Float16 f16x2 __attribute__((ext_vector_type(2)));
typedef _Float16 f16x4 __attribute__((ext_vector_type(4)));
typedef _Float16 f16x8 __attribute__((ext_vector_type(8)));
typedef float f32x4 __attribute__((ext_vector_type(4)));
typedef unsigned int u32x4 __attribute__((ext_vector_type(4)));

static __device__ __forceinline__ float sigm(float z) {
  return __builtin_amdgcn_rcpf(1.0f + __expf(-z));
}

static __device__ __forceinline__ unsigned pk2(float a, float b) {
  f16x2 t;
  t[0] = (f16)a;
  t[1] = (f16)b;
  return __builtin_bit_cast(unsigned, t);
}

// ---------------------------------------------------------------------------
// prep: build masked f16 weights, pre-swizzled to MFMA A-fragment order.
// Fragment order: lane = quad*16 + row15, elems 8; col = ks*32 + quad*8 + e.
//  WpT [L][rt=row/16][ks=0..39][512]    row=j_o*20+ch_o, mask j_i<=j_o (hist A)
//  WsT [L][i][tile=ch/16][ks=0..4][512] cols rel to HC*(i&~7), ch padded ->32 (seq A)
//  W1T [i][tile][ks=0..1][512]          cols = spins, mask c<i (seq L1 A)
//  W6bT[m*8+t][512]                     16 tp rows x 32 k, mask t<=tp,k<20 (z6 A)
//  W6T [m][ks=0..39][512]               16 tp rows (8 real), mask j_i<=I+tp
// ---------------------------------------------------------------------------
__global__ __launch_bounds__(256) void prep(
    const float* __restrict__ W1, const float* __restrict__ W2,
    const float* __restrict__ W3, const float* __restrict__ W4,
    const float* __restrict__ W5, const float* __restrict__ W6,
    f16* __restrict__ WpT, f16* __restrict__ WsT, f16* __restrict__ W1T,
    f16* __restrict__ W6bT, f16* __restrict__ W6T) {
  __shared__ float row[HTOT];
  int bid = blockIdx.x;
  if (bid < 4 * HTOT) {
    int L = bid / HTOT, cp = bid % HTOT;
    int j_o = cp / HC, ch_o = cp % HC;
    const float* Wsrc = (L == 0) ? W2 : (L == 1) ? W3 : (L == 2) ? W4 : W5;
    const float* src = Wsrc + (size_t)(ch_o * NS + j_o) * HTOT;
    for (int k = threadIdx.x; k < HTOT; k += 256) row[k] = src[k];
    __syncthreads();
    // WpT: this source row is A-row cp -> rt = cp>>4, row15 = cp&15
    {
      int rt = cp >> 4, rl = cp & 15;
      f16* dwp = WpT + (size_t)(L * 80 + rt) * 40 * 512;
      for (int xp = threadIdx.x; xp < HTOT; xp += 256) {
        int j_i = xp / HC, ch_i = xp % HC;
        f16 v = (f16)((j_i <= j_o) ? row[ch_i * NS + j_i] : 0.0f);
        int ks = xp >> 5, q = (xp >> 3) & 3, e = xp & 7;
        dwp[ks * 512 + (q * 16 + rl) * 8 + e] = v;
      }
    }
    // WsT: A-row ch_o of spin j_o, cols relative to block base HC*(j_o&~7)
    {
      int base = HC * (j_o & ~7);
      int tile = ch_o >> 4, tl = ch_o & 15;
      f16* dws = WsT + (size_t)(((L * NS + j_o) * 2 + tile) * 5) * 512;
      for (int kr = threadIdx.x; kr < 160; kr += 256) {
        int xp = base + kr;
        int j_i = xp / HC, ch_i = xp % HC;
        f16 v = (f16)((j_i <= j_o) ? row[ch_i * NS + j_i] : 0.0f);
        int ks = kr >> 5, q = (kr >> 3) & 3, e = kr & 7;
        dws[ks * 512 + (q * 16 + tl) * 8 + e] = v;
      }
      if (ch_o < 12) {  // zero pad rows ch=20..31 (tile1 rows 4..15)
        int zl = (20 + ch_o) & 15;
        f16* dz = WsT + (size_t)(((L * NS + j_o) * 2 + 1) * 5) * 512;
        for (int kr = threadIdx.x; kr < 160; kr += 256) {
          int ks = kr >> 5, q = (kr >> 3) & 3, e = kr & 7;
          dz[ks * 512 + (q * 16 + zl) * 8 + e] = (f16)0.0f;
        }
      }
    }
  } else if (bid < 4 * HTOT + NS) {
    int j_o = bid - 4 * HTOT;
    for (int idx = threadIdx.x; idx < 32 * 64; idx += 256) {
      int ch = idx >> 6, c = idx & 63;
      float v = (ch < HC && c < j_o) ? W1[((size_t)ch * NS + j_o) * NS + c] : 0.0f;
      int tile = ch >> 4, tl = ch & 15, ks = c >> 5, q = (c >> 3) & 3, e = c & 7;
      W1T[(size_t)((j_o * 2 + tile) * 2 + ks) * 512 + (q * 16 + tl) * 8 + e] = (f16)v;
    }
  } else if (bid < 4 * HTOT + NS + 8) {
    int m = bid - (4 * HTOT + NS);
    int I = m * KB;
    for (int idx = threadIdx.x; idx < 8 * 16 * 32; idx += 256) {
      int t = idx >> 9, tp = (idx >> 5) & 15, k = idx & 31;
      float v = (tp < 8 && k < HC && t <= tp)
                    ? W6[(size_t)(I + tp) * HTOT + k * NS + (I + t)]
                    : 0.0f;
      int q = k >> 3, e = k & 7;
      W6bT[(size_t)(m * 8 + t) * 512 + (q * 16 + tp) * 8 + e] = (f16)v;
    }
  } else {
    int m = bid - (4 * HTOT + NS + 8);
    int I = m * KB;
    for (int idx = threadIdx.x; idx < 16 * HTOT; idx += 256) {
      int tp = idx / HTOT, xp = idx % HTOT;
      int j_i = xp / HC, ch_i = xp % HC;
      float v = (tp < 8 && j_i <= I + tp)
                    ? W6[(size_t)(I + tp) * HTOT + ch_i * NS + j_i]
                    : 0.0f;
      int ks = xp >> 5, q = (xp >> 3) & 3, e = xp & 7;
      W6T[(size_t)(m * 40 + ks) * 512 + (q * 16 + tp) * 8 + e] = (f16)v;
    }
  }
}

// ---------------------------------------------------------------------------
// gemm_hist: history GEMMs for block starting at spin I, all 5 layer-slots.
//  L<4 : ZgH[L*160+c][b] (f16) = sum_{k<20I} W(L)[20I+c][k] * AH[L][k][b]
//  L==4: Zg6[tp][b]      (f32) = sum_{k<20I} W6row(tp)[k]  * AH[4][k][b]
// A loads coalesced from fragment-order WpT/W6T; AH is raw B-fragment layout.
// Unsplit (R9 form): K-split dropped — its 2-partial buffer would re-force
// batch chunking, which costs ~8x more than the split saves.
// ---------------------------------------------------------------------------
__global__ __launch_bounds__(256) void gemm_hist(
    const f16* __restrict__ WpT, const f16* __restrict__ W6T,
    const f16* __restrict__ AH, f16* __restrict__ ZgH,
    float* __restrict__ Zg6, int I, int BS) {
  const int L = blockIdx.y;
  const int tid = threadIdx.x;
  const int lane = tid & 63;
  const int w = tid >> 6;
  const int l15 = tid & 15;
  const int quad = lane >> 4;
  const int m = I >> 3;
  const int G32 = (HC * I) >> 5;

  if (L == 4) {
    const int b0 = blockIdx.x * 64 + w * 16;
    f32x4 acc = (f32x4){0.f, 0.f, 0.f, 0.f};
    const f16* ap = W6T + (size_t)(m * 40) * 512 + lane * 8;
    const f16* bp = AH + ((size_t)(4 * 160 + quad) * BS + b0 + l15) * 8;
#pragma unroll 2
    for (int ks = 0; ks < G32; ++ks) {
      f16x8 af = *(const f16x8*)ap;
      f16x8 bf = *(const f16x8*)bp;
      acc = __builtin_amdgcn_mfma_f32_16x16x32_f16(af, bf, acc, 0, 0, 0);
      ap += 512;
      bp += (size_t)4 * BS * 8;
    }
#pragma unroll
    for (int r = 0; r < 4; ++r)
      Zg6[(size_t)(quad * 4 + r) * BS + b0 + l15] = acc[r];
    return;
  }

  const int wm = w & 1, wn = w >> 1;
  const int b0 = blockIdx.x * 64 + wn * 32;

  f32x4 acc[5][2];
#pragma unroll
  for (int mt = 0; mt < 5; ++mt) {
    acc[mt][0] = (f32x4){0.f, 0.f, 0.f, 0.f};
    acc[mt][1] = (f32x4){0.f, 0.f, 0.f, 0.f};
  }

  const f16* ap = WpT + (size_t)((L * 80 + 10 * m + 5 * wm) * 40) * 512 + lane * 8;
  const f16* bp = AH + ((size_t)(L * 160 + quad) * BS + b0 + l15) * 8;

#pragma unroll 2
  for (int ks = 0; ks < G32; ++ks) {
    f16x8 bf0 = *(const f16x8*)(bp);
    f16x8 bf1 = *(const f16x8*)(bp + 128);
    f16x8 af[5];
#pragma unroll
    for (int mt = 0; mt < 5; ++mt)
      af[mt] = *(const f16x8*)(ap + (size_t)mt * 40 * 512);
#pragma unroll
    for (int mt = 0; mt < 5; ++mt) {
      acc[mt][0] = __builtin_amdgcn_mfma_f32_16x16x32_f16(af[mt], bf0, acc[mt][0], 0, 0, 0);
      acc[mt][1] = __builtin_amdgcn_mfma_f32_16x16x32_f16(af[mt], bf1, acc[mt][1], 0, 0, 0);
    }
    ap += 512;
    bp += (size_t)4 * BS * 8;
  }

#pragma unroll
  for (int mt = 0; mt < 5; ++mt)
#pragma unroll
    for (int nt = 0; nt < 2; ++nt)
#pragma unroll
      for (int r = 0; r < 4; ++r) {
        int c = wm * 80 + mt * 16 + quad * 4 + r;
        int b = b0 + nt * 16 + l15;
        ZgH[(size_t)(L * 160 + c) * BS + b] = (f16)acc[mt][nt][r];
      }
}

// ---------------------------------------------------------------------------
// seq_block v7 (R9 structure, latency-pipelined MFMA phases): 1 wave, BT=16.
// Full t-unroll (cross-t load hoisting is the latency-hiding mechanism — R14
// proved rolling this loop costs +70%); Zg post-added from SINGLE f16 buffer
// (one ushort load per (L,r); f16 rounding validated R16/R17); u preloaded;
// z6 via shfl from layer-5 C-regs; sampled bit carried in reg; s_ws packed i8.
// ---------------------------------------------------------------------------
__global__ __launch_bounds__(64) void seq_block(
    const f16* __restrict__ WsT, const f16* __restrict__ W1T,
    const f16* __restrict__ W6bT, f16* __restrict__ AH,
    const f16* __restrict__ ZgH, const float* __restrict__ Zg6,
    signed char* __restrict__ s_ws, const float* __restrict__ u,
    float* __restrict__ outp, int I, int BS, int b0) {
  __shared__ __align__(16) f16 aL[5][BT][184];   // 29440 B
  __shared__ __align__(16) f16 sL[BT][72];       // 2304 B -> 31744 B total

  const int lane = threadIdx.x;
  const int l15 = lane & 15;            // MFMA col = batch row in WG
  const int quad = lane >> 4;           // MFMA k-group / C row-group
  const int m = I >> 3;
  const int bcol = blockIdx.x * BT + l15;
  const int bg = b0 + bcol;

  // early global loads: u for all 8 spins, z6 accumulator init
  float uv[KB];
#pragma unroll
  for (int t = 0; t < KB; ++t) uv[t] = u[(size_t)(I + t) * NB + bg];
  f32x4 acc6;
#pragma unroll
  for (int r = 0; r < 4; ++r)
    acc6[r] = Zg6[(size_t)(quad * 4 + r) * BS + bcol];

  // zero LDS (masked-weight / K-pad tails must read as 0)
  {
    f16x8 z = {};
    f16x8* pa = (f16x8*)&aL[0][0][0];
    for (int k = lane; k < (5 * BT * 184) / 8; k += 64) pa[k] = z;
    f16x8* ps = (f16x8*)&sL[0][0];
    for (int k = lane; k < (BT * 72) / 8; k += 64) ps[k] = z;
  }
  __syncthreads();

  // load sampled-bit history j < I (i8 -> f16)
  for (int c8 = quad; c8 < (I >> 3); c8 += 4) {
    unsigned long long raw = *(const unsigned long long*)(
        s_ws + (size_t)(blockIdx.x * BT + l15) * NS + c8 * 8);
    f16x8 v;
#pragma unroll
    for (int e = 0; e < 8; ++e) {
      signed char c = (signed char)(raw >> (8 * e));
      v[e] = (f16)(float)c;
    }
    *(f16x8*)&sL[l15][c8 * 8] = v;
  }
  __syncthreads();

  float bitv = 0.0f;  // freshest sampled bit (spin I+t-1), per batch-column

#pragma unroll
  for (int t = 0; t < KB; ++t) {
    const int i = I + t;

    // ---- prefetch this t's Zg rows (single f16 buffer), all 4 layers ----
    float zg0[4][4], zg1[4][4];
#pragma unroll
    for (int L = 0; L < 4; ++L)
#pragma unroll
      for (int r = 0; r < 4; ++r) {
        zg0[L][r] = (float)ZgH[(size_t)(L * 160 + t * HC + quad * 4 + r) * BS + bcol];
        zg1[L][r] = (quad == 0)
            ? (float)ZgH[(size_t)(L * 160 + t * HC + 16 + r) * BS + bcol]
            : 0.f;
      }

    // ---- layer 1: z[32ch x 16b] = W1(i) (32x64) . sL (64x16) ----
    {
      f32x4 z0 = (f32x4){0.f, 0.f, 0.f, 0.f};
      f32x4 z1 = (f32x4){0.f, 0.f, 0.f, 0.f};
      const int KS1 = (i + 31) >> 5;
      const f16* w0 = W1T + (size_t)(i * 2) * 2 * 512 + lane * 8;
      for (int ks = 0; ks < KS1; ++ks) {
        f16x8 bf = *(const f16x8*)&sL[l15][quad * 8 + 32 * ks];
        if (t > 0 && ks == ((i - 1) >> 5) && quad == (((I & 31) + t - 1) >> 3))
          bf[(t - 1) & 7] = (f16)bitv;  // freshest bit, not yet LDS-visible
        f16x8 a0 = *(const f16x8*)(w0 + ks * 512);
        f16x8 a1 = *(const f16x8*)(w0 + (2 + ks) * 512);
        z0 = __builtin_amdgcn_mfma_f32_16x16x32_f16(a0, bf, z0, 0, 0, 0);
        z1 = __builtin_amdgcn_mfma_f32_16x16x32_f16(a1, bf, z1, 0, 0, 0);
      }
      f16x4 o0;
#pragma unroll
      for (int r = 0; r < 4; ++r) o0[r] = (f16)sigm(z0[r]);
      *(f16x4*)&aL[0][l15][t * HC + quad * 4] = o0;
      if (quad == 0) {
        f16x4 o1;
#pragma unroll
        for (int r = 0; r < 4; ++r) o1[r] = (f16)sigm(z1[r]);
        *(f16x4*)&aL[0][l15][t * HC + 16] = o1;
      }
    }
    __syncthreads();

    // ---- layers 2..5: z = W(L,i) (32xK) . aL[L] (Kx16), then += Zg ----
    const int KS = (HC * (t + 1) + 31) >> 5;  // compile-time under unroll
    float a5o0[4], a5o1[4];
#pragma unroll
    for (int L = 0; L < 4; ++L) {
      f32x4 z0 = (f32x4){0.f, 0.f, 0.f, 0.f};
      f32x4 z1 = (f32x4){0.f, 0.f, 0.f, 0.f};
      const f16* wb = WsT + (size_t)((L * NS + i) * 2) * 5 * 512 + lane * 8;
#pragma unroll
      for (int ks = 0; ks < KS; ++ks) {
        f16x8 bf = *(const f16x8*)&aL[L][l15][quad * 8 + 32 * ks];
        f16x8 a0 = *(const f16x8*)(wb + ks * 512);
        f16x8 a1 = *(const f16x8*)(wb + (5 + ks) * 512);
        z0 = __builtin_amdgcn_mfma_f32_16x16x32_f16(a0, bf, z0, 0, 0, 0);
        z1 = __builtin_amdgcn_mfma_f32_16x16x32_f16(a1, bf, z1, 0, 0, 0);
      }
      f16x4 o0;
#pragma unroll
      for (int r = 0; r < 4; ++r) {
        float v = sigm(z0[r] + zg0[L][r]);
        o0[r] = (f16)v;
        if (L == 3) a5o0[r] = v;
      }
      *(f16x4*)&aL[L + 1][l15][t * HC + quad * 4] = o0;
      {
        f16x4 o1;
#pragma unroll
        for (int r = 0; r < 4; ++r) {
          float v = sigm(z1[r] + zg1[L][r]);
          o1[r] = (f16)v;
          if (L == 3) a5o1[r] = v;
        }
        if (quad == 0) *(f16x4*)&aL[L + 1][l15][t * HC + 16] = o1;
      }
      if (L < 3) __syncthreads();  // aL[4] never cross-read before writeout
    }

    // ---- z6: B-frag = fresh a5 only (W6bT zero-masks k>=20) via shfl ----
    {
      unsigned p0 = pk2(a5o0[0], a5o0[1]);
      unsigned p1 = pk2(a5o0[2], a5o0[3]);
      unsigned p2 = pk2(a5o1[0], a5o1[1]);
      unsigned p3 = pk2(a5o1[2], a5o1[3]);
      int src1 = (((quad * 2) & 3) << 4) + l15;
      int src2 = src1 + 16;
      unsigned d0 = (unsigned)__shfl((int)p0, src1, 64);
      unsigned d1 = (unsigned)__shfl((int)p1, src1, 64);
      unsigned d2 = (unsigned)__shfl((int)p0, src2, 64);
      unsigned d3 = (unsigned)__shfl((int)p1, src2, 64);
      unsigned e0 = (unsigned)__shfl((int)p2, src1, 64);
      unsigned e1 = (unsigned)__shfl((int)p3, src1, 64);
      u32x4 bv = (quad < 2) ? (u32x4){d0, d1, d2, d3} : (u32x4){e0, e1, e0, e1};
      f16x8 b5 = __builtin_bit_cast(f16x8, bv);
      f16x8 a6 = *(const f16x8*)(W6bT + (size_t)(m * 8 + t) * 512 + lane * 8);
      acc6 = __builtin_amdgcn_mfma_f32_16x16x32_f16(a6, b5, acc6, 0, 0, 0);
      // extract row t (owner quad = t>>2, reg t&3; static under unroll)
      float x = sigm(acc6[t & 3]);
      if (quad == (t >> 2)) {
        outp[(size_t)bg * NS + i] = x;  // final output col i == sampling-time x
        sL[l15][i] = (f16)((x >= uv[t]) ? 1.0f : -1.0f);
      }
      float xall = __shfl(x, ((t >> 2) << 4) + l15, 64);
      bitv = (xall >= uv[t]) ? 1.0f : -1.0f;
    }
    // no end-of-t barrier: t+1 L1 gets the fresh bit from bitv; older sL writes
    // are >= 4 syncs old; aL[4] writes only read after the final barrier.
  }
  __syncthreads();

  // ---- bulk writeout: block activations -> global AH ([L][g][b][e]), s bits ----
  for (int w = lane; w < 5 * 20 * BT; w += 64) {
    int rr = w & 15;
    int q = w >> 4;            // 0..99
    int L = q / 20, x8 = q % 20;
    f16x8 v = *(const f16x8*)&aL[L][rr][x8 * 8];
    int gg = ((HC * I) >> 3) + x8;
    *(f16x8*)(AH + ((size_t)(L * 160 + gg) * BS + blockIdx.x * BT + rr) * 8) = v;
  }
  if (lane < BT) {
    unsigned long long pk = 0;
#pragma unroll
    for (int e = 0; e < 8; ++e) {
      float f = (float)sL[lane][I + e];
      unsigned char c = (unsigned char)(signed char)((f >= 0.f) ? 1 : -1);
      pk |= (unsigned long long)c << (8 * e);
    }
    *(unsigned long long*)(s_ws + (size_t)(blockIdx.x * BT + lane) * NS + I) = pk;
  }
}

// ---------------------------------------------------------------------------
extern "C" void kernel_launch(void* const* d_in, const int* in_sizes, int n_in,
                              void* d_out, int out_size, void* d_ws, size_t ws_size,
                              hipStream_t stream) {
  (void)in_sizes; (void)n_in; (void)out_size;
  const float* u  = (const float*)d_in[1];
  const float* W1 = (const float*)d_in[2];
  const float* W2 = (const float*)d_in[3];
  const float* W3 = (const float*)d_in[4];
  const float* W4 = (const float*)d_in[5];
  const float* W5 = (const float*)d_in[6];
  const float* W6 = (const float*)d_in[7];
  float* outp = (float*)d_out;

  const size_t wpTEls  = (size_t)4 * 80 * 40 * 512;      // 6.55M  hist A
  const size_t wsTEls  = (size_t)4 * NS * 2 * 5 * 512;   // 1.31M  seq A
  const size_t w1TEls  = (size_t)NS * 2 * 2 * 512;       // 131K   seq L1 A
  const size_t w6bTEls = (size_t)64 * 512;               // 33K    seq z6 A
  const size_t w6TEls  = (size_t)8 * 40 * 512;           // 164K   hist z6 A
  const size_t wEls = wpTEls + wsTEls + w1TEls + w6bTEls + w6TEls;
  const size_t wBytes = wEls * sizeof(f16);

  // per-row: AH 12800 + ZgH 1280 (f16) + Zg6 64 (f32) + s_ws 64 (i8) = 14208 B
  // -> BS = 16384 single chunk (rem ~= 235 MB per R15's measured budget).
  size_t rem = (ws_size > wBytes + 4096) ? (ws_size - wBytes - 4096) : 0;
  long long bs = (long long)(rem / 14208);
  bs = (bs / 64) * 64;
  if (bs > NB) bs = NB;
  if (bs < 64) bs = 64;
  const int BS = (int)bs;

  f16* WpT   = (f16*)d_ws;
  f16* WsT   = WpT + wpTEls;
  f16* W1T   = WsT + wsTEls;
  f16* W6bT  = W1T + w1TEls;
  f16* W6T   = W6bT + w6bTEls;
  f16* AH    = W6T + w6TEls;
  f16* ZgH   = AH + (size_t)5 * 160 * BS * 8;            // [640][BS] f16
  float* Zg6 = (float*)(ZgH + (size_t)640 * BS);
  signed char* s_ws = (signed char*)(Zg6 + (size_t)16 * BS);

  prep<<<dim3(4 * HTOT + NS + 16), dim3(256), 0, stream>>>(
      W1, W2, W3, W4, W5, W6, WpT, WsT, W1T, W6bT, W6T);

  for (int c0 = 0; c0 < NB; c0 += BS) {
    int nr = NB - c0; if (nr > BS) nr = BS;
    for (int m = 0; m < NS / KB; ++m) {
      const int I = m * KB;
      gemm_hist<<<dim3(nr / 64, 5), dim3(256), 0, stream>>>(
          WpT, W6T, AH, ZgH, Zg6, I, BS);
      seq_block<<<dim3(nr / BT), dim3(64), 0, stream>>>(
          WsT, W1T, W6bT, AH, ZgH, Zg6, s_ws, u, outp, I, BS, c0);
    }
  }
}

// Round 15
// 702.580 us; speedup vs baseline: 2.4116x; 1.3179x over previous
//
#include <hip/hip_runtime.h>

// Autoregressive masked net sampler.
//  - output col i == sampling-time x[:,i]  (masks: out i depends on spins < i only)
//  - spin blocks of KB=8: history part = dense GEMM (MFMA f16), intra-block part
//    sequential per-row (rows independent -> no grid sync).
// R9: 1154us. R10-R13: fusion abandoned (VGPR cap). R14: seq t-roll refuted
//     (full unroll = the latency-hider). R15-R17: K-split partial layouts all
//     regressed via chunking / half-line amplification; K-split dropped.
// R18: SINGLE chunk via 14208 B/row (f16 Zg, i8 s_ws): 926us (best). Profile:
//     seq FETCH 43.7MB = 2x the 21MB f16 ZgH -> half-line amplification (16
//     lanes x 2B = 32B of each 64B line); ~65us of seq's 106 is Zg traffic.
// R19 (this): pair-interleave ZgH: u32 [320][BS] holds f16 row-pair (2k,2k+1)
//     per batch col. All row indices pair-aligned. Hist writes 2 u32 (full-line
//     stores); seq loads 2 u32 per (L,quad) (full-line, half the loads).
//     Footprint unchanged -> single chunk retained.

#define NS   64          // spins
#define HC   20          // hidden channels per spin
#define HTOT 1280        // NS*HC
#define NB   16384       // batch
#define KB   8           // spins per block (8 blocks)
#define BT   16          // batch rows per seq workgroup (MFMA N-tile)

typedef _Float16 f16;
typedef _Float16 f16x2 __attribute__((ext_vector_type(2)));
typedef _Float16 f16x4 __attribute__((ext_vector_type(4)));
typedef _Float16 f16x8 __attribute__((ext_vector_type(8)));
typedef float f32x4 __attribute__((ext_vector_type(4)));
typedef unsigned int u32x4 __attribute__((ext_vector_type(4)));

static __device__ __forceinline__ float sigm(float z) {
  return __builtin_amdgcn_rcpf(1.0f + __expf(-z));
}

static __device__ __forceinline__ unsigned pk2(float a, float b) {
  f16x2 t;
  t[0] = (f16)a;
  t[1] = (f16)b;
  return __builtin_bit_cast(unsigned, t);
}

// ---------------------------------------------------------------------------
// prep: build masked f16 weights, pre-swizzled to MFMA A-fragment order.
// Fragment order: lane = quad*16 + row15, elems 8; col = ks*32 + quad*8 + e.
//  WpT [L][rt=row/16][ks=0..39][512]    row=j_o*20+ch_o, mask j_i<=j_o (hist A)
//  WsT [L][i][tile=ch/16][ks=0..4][512] cols rel to HC*(i&~7), ch padded ->32 (seq A)
//  W1T [i][tile][ks=0..1][512]          cols = spins, mask c<i (seq L1 A)
//  W6bT[m*8+t][512]                     16 tp rows x 32 k, mask t<=tp,k<20 (z6 A)
//  W6T [m][ks=0..39][512]               16 tp rows (8 real), mask j_i<=I+tp
// ---------------------------------------------------------------------------
__global__ __launch_bounds__(256) void prep(
    const float* __restrict__ W1, const float* __restrict__ W2,
    const float* __restrict__ W3, const float* __restrict__ W4,
    const float* __restrict__ W5, const float* __restrict__ W6,
    f16* __restrict__ WpT, f16* __restrict__ WsT, f16* __restrict__ W1T,
    f16* __restrict__ W6bT, f16* __restrict__ W6T) {
  __shared__ float row[HTOT];
  int bid = blockIdx.x;
  if (bid < 4 * HTOT) {
    int L = bid / HTOT, cp = bid % HTOT;
    int j_o = cp / HC, ch_o = cp % HC;
    const float* Wsrc = (L == 0) ? W2 : (L == 1) ? W3 : (L == 2) ? W4 : W5;
    const float* src = Wsrc + (size_t)(ch_o * NS + j_o) * HTOT;
    for (int k = threadIdx.x; k < HTOT; k += 256) row[k] = src[k];
    __syncthreads();
    // WpT: this source row is A-row cp -> rt = cp>>4, row15 = cp&15
    {
      int rt = cp >> 4, rl = cp & 15;
      f16* dwp = WpT + (size_t)(L * 80 + rt) * 40 * 512;
      for (int xp = threadIdx.x; xp < HTOT; xp += 256) {
        int j_i = xp / HC, ch_i = xp % HC;
        f16 v = (f16)((j_i <= j_o) ? row[ch_i * NS + j_i] : 0.0f);
        int ks = xp >> 5, q = (xp >> 3) & 3, e = xp & 7;
        dwp[ks * 512 + (q * 16 + rl) * 8 + e] = v;
      }
    }
    // WsT: A-row ch_o of spin j_o, cols relative to block base HC*(j_o&~7)
    {
      int base = HC * (j_o & ~7);
      int tile = ch_o >> 4, tl = ch_o & 15;
      f16* dws = WsT + (size_t)(((L * NS + j_o) * 2 + tile) * 5) * 512;
      for (int kr = threadIdx.x; kr < 160; kr += 256) {
        int xp = base + kr;
        int j_i = xp / HC, ch_i = xp % HC;
        f16 v = (f16)((j_i <= j_o) ? row[ch_i * NS + j_i] : 0.0f);
        int ks = kr >> 5, q = (kr >> 3) & 3, e = kr & 7;
        dws[ks * 512 + (q * 16 + tl) * 8 + e] = v;
      }
      if (ch_o < 12) {  // zero pad rows ch=20..31 (tile1 rows 4..15)
        int zl = (20 + ch_o) & 15;
        f16* dz = WsT + (size_t)(((L * NS + j_o) * 2 + 1) * 5) * 512;
        for (int kr = threadIdx.x; kr < 160; kr += 256) {
          int ks = kr >> 5, q = (kr >> 3) & 3, e = kr & 7;
          dz[ks * 512 + (q * 16 + zl) * 8 + e] = (f16)0.0f;
        }
      }
    }
  } else if (bid < 4 * HTOT + NS) {
    int j_o = bid - 4 * HTOT;
    for (int idx = threadIdx.x; idx < 32 * 64; idx += 256) {
      int ch = idx >> 6, c = idx & 63;
      float v = (ch < HC && c < j_o) ? W1[((size_t)ch * NS + j_o) * NS + c] : 0.0f;
      int tile = ch >> 4, tl = ch & 15, ks = c >> 5, q = (c >> 3) & 3, e = c & 7;
      W1T[(size_t)((j_o * 2 + tile) * 2 + ks) * 512 + (q * 16 + tl) * 8 + e] = (f16)v;
    }
  } else if (bid < 4 * HTOT + NS + 8) {
    int m = bid - (4 * HTOT + NS);
    int I = m * KB;
    for (int idx = threadIdx.x; idx < 8 * 16 * 32; idx += 256) {
      int t = idx >> 9, tp = (idx >> 5) & 15, k = idx & 31;
      float v = (tp < 8 && k < HC && t <= tp)
                    ? W6[(size_t)(I + tp) * HTOT + k * NS + (I + t)]
                    : 0.0f;
      int q = k >> 3, e = k & 7;
      W6bT[(size_t)(m * 8 + t) * 512 + (q * 16 + tp) * 8 + e] = (f16)v;
    }
  } else {
    int m = bid - (4 * HTOT + NS + 8);
    int I = m * KB;
    for (int idx = threadIdx.x; idx < 16 * HTOT; idx += 256) {
      int tp = idx / HTOT, xp = idx % HTOT;
      int j_i = xp / HC, ch_i = xp % HC;
      float v = (tp < 8 && j_i <= I + tp)
                    ? W6[(size_t)(I + tp) * HTOT + ch_i * NS + j_i]
                    : 0.0f;
      int ks = xp >> 5, q = (xp >> 3) & 3, e = xp & 7;
      W6T[(size_t)(m * 40 + ks) * 512 + (q * 16 + tp) * 8 + e] = (f16)v;
    }
  }
}

// ---------------------------------------------------------------------------
// gemm_hist: history GEMMs for block starting at spin I, all 5 layer-slots.
//  L<4 : Zp32[(L*80+pr)][b] = pk2(row 2pr, row 2pr+1)  (pair-interleaved f16)
//  L==4: Zg6[tp][b] (f32) = sum_{k<20I} W6row(tp)[k] * AH[4][k][b]
// A loads coalesced from fragment-order WpT/W6T; AH is raw B-fragment layout.
// Unsplit (R9 form). Pair-packed u32 stores -> full 64B-line writes.
// ---------------------------------------------------------------------------
__global__ __launch_bounds__(256) void gemm_hist(
    const f16* __restrict__ WpT, const f16* __restrict__ W6T,
    const f16* __restrict__ AH, f16* __restrict__ ZgH,
    float* __restrict__ Zg6, int I, int BS) {
  const int L = blockIdx.y;
  const int tid = threadIdx.x;
  const int lane = tid & 63;
  const int w = tid >> 6;
  const int l15 = tid & 15;
  const int quad = lane >> 4;
  const int m = I >> 3;
  const int G32 = (HC * I) >> 5;

  if (L == 4) {
    const int b0 = blockIdx.x * 64 + w * 16;
    f32x4 acc = (f32x4){0.f, 0.f, 0.f, 0.f};
    const f16* ap = W6T + (size_t)(m * 40) * 512 + lane * 8;
    const f16* bp = AH + ((size_t)(4 * 160 + quad) * BS + b0 + l15) * 8;
#pragma unroll 2
    for (int ks = 0; ks < G32; ++ks) {
      f16x8 af = *(const f16x8*)ap;
      f16x8 bf = *(const f16x8*)bp;
      acc = __builtin_amdgcn_mfma_f32_16x16x32_f16(af, bf, acc, 0, 0, 0);
      ap += 512;
      bp += (size_t)4 * BS * 8;
    }
#pragma unroll
    for (int r = 0; r < 4; ++r)
      Zg6[(size_t)(quad * 4 + r) * BS + b0 + l15] = acc[r];
    return;
  }

  const int wm = w & 1, wn = w >> 1;
  const int b0 = blockIdx.x * 64 + wn * 32;

  f32x4 acc[5][2];
#pragma unroll
  for (int mt = 0; mt < 5; ++mt) {
    acc[mt][0] = (f32x4){0.f, 0.f, 0.f, 0.f};
    acc[mt][1] = (f32x4){0.f, 0.f, 0.f, 0.f};
  }

  const f16* ap = WpT + (size_t)((L * 80 + 10 * m + 5 * wm) * 40) * 512 + lane * 8;
  const f16* bp = AH + ((size_t)(L * 160 + quad) * BS + b0 + l15) * 8;

#pragma unroll 2
  for (int ks = 0; ks < G32; ++ks) {
    f16x8 bf0 = *(const f16x8*)(bp);
    f16x8 bf1 = *(const f16x8*)(bp + 128);
    f16x8 af[5];
#pragma unroll
    for (int mt = 0; mt < 5; ++mt)
      af[mt] = *(const f16x8*)(ap + (size_t)mt * 40 * 512);
#pragma unroll
    for (int mt = 0; mt < 5; ++mt) {
      acc[mt][0] = __builtin_amdgcn_mfma_f32_16x16x32_f16(af[mt], bf0, acc[mt][0], 0, 0, 0);
      acc[mt][1] = __builtin_amdgcn_mfma_f32_16x16x32_f16(af[mt], bf1, acc[mt][1], 0, 0, 0);
    }
    ap += 512;
    bp += (size_t)4 * BS * 8;
  }

  // pair-packed u32 stores: rows c0=wm*80+mt*16+quad*4 (+0,1) and (+2,3)
  unsigned* Zp32 = (unsigned*)ZgH;
#pragma unroll
  for (int mt = 0; mt < 5; ++mt)
#pragma unroll
    for (int nt = 0; nt < 2; ++nt) {
      int pr = wm * 40 + mt * 8 + quad * 2;   // pair index within layer
      int b = b0 + nt * 16 + l15;
      Zp32[(size_t)(L * 80 + pr) * BS + b] = pk2(acc[mt][nt][0], acc[mt][nt][1]);
      Zp32[(size_t)(L * 80 + pr + 1) * BS + b] = pk2(acc[mt][nt][2], acc[mt][nt][3]);
    }
}

// ---------------------------------------------------------------------------
// seq_block v7 (R9 structure, latency-pipelined MFMA phases): 1 wave, BT=16.
// Full t-unroll (cross-t load hoisting is the latency-hiding mechanism — R14
// proved rolling this loop costs +70%); Zg post-added from PAIR-INTERLEAVED
// f16 buffer: two u32 loads per (L,quad) give all 4 rows, full 64B-line
// consumption (R18's half-line amplification removed); u preloaded; z6 via
// shfl from layer-5 C-regs; sampled bit carried in reg; s_ws packed i8.
// ---------------------------------------------------------------------------
__global__ __launch_bounds__(64) void seq_block(
    const f16* __restrict__ WsT, const f16* __restrict__ W1T,
    const f16* __restrict__ W6bT, f16* __restrict__ AH,
    const f16* __restrict__ ZgH, const float* __restrict__ Zg6,
    signed char* __restrict__ s_ws, const float* __restrict__ u,
    float* __restrict__ outp, int I, int BS, int b0) {
  __shared__ __align__(16) f16 aL[5][BT][184];   // 29440 B
  __shared__ __align__(16) f16 sL[BT][72];       // 2304 B -> 31744 B total

  const int lane = threadIdx.x;
  const int l15 = lane & 15;            // MFMA col = batch row in WG
  const int quad = lane >> 4;           // MFMA k-group / C row-group
  const int m = I >> 3;
  const int bcol = blockIdx.x * BT + l15;
  const int bg = b0 + bcol;
  const unsigned* Zp = (const unsigned*)ZgH;  // [320 pairs][BS] u32 view

  // early global loads: u for all 8 spins, z6 accumulator init
  float uv[KB];
#pragma unroll
  for (int t = 0; t < KB; ++t) uv[t] = u[(size_t)(I + t) * NB + bg];
  f32x4 acc6;
#pragma unroll
  for (int r = 0; r < 4; ++r)
    acc6[r] = Zg6[(size_t)(quad * 4 + r) * BS + bcol];

  // zero LDS (masked-weight / K-pad tails must read as 0)
  {
    f16x8 z = {};
    f16x8* pa = (f16x8*)&aL[0][0][0];
    for (int k = lane; k < (5 * BT * 184) / 8; k += 64) pa[k] = z;
    f16x8* ps = (f16x8*)&sL[0][0];
    for (int k = lane; k < (BT * 72) / 8; k += 64) ps[k] = z;
  }
  __syncthreads();

  // load sampled-bit history j < I (i8 -> f16)
  for (int c8 = quad; c8 < (I >> 3); c8 += 4) {
    unsigned long long raw = *(const unsigned long long*)(
        s_ws + (size_t)(blockIdx.x * BT + l15) * NS + c8 * 8);
    f16x8 v;
#pragma unroll
    for (int e = 0; e < 8; ++e) {
      signed char c = (signed char)(raw >> (8 * e));
      v[e] = (f16)(float)c;
    }
    *(f16x8*)&sL[l15][c8 * 8] = v;
  }
  __syncthreads();

  float bitv = 0.0f;  // freshest sampled bit (spin I+t-1), per batch-column

#pragma unroll
  for (int t = 0; t < KB; ++t) {
    const int i = I + t;

    // ---- prefetch this t's Zg rows (pair-interleaved u32), all 4 layers ----
    float zg0[4][4], zg1[4][4];
#pragma unroll
    for (int L = 0; L < 4; ++L) {
      int prb = L * 80 + t * 10;
      unsigned v01 = Zp[(size_t)(prb + quad * 2) * BS + bcol];
      unsigned v23 = Zp[(size_t)(prb + quad * 2 + 1) * BS + bcol];
      f16x2 p01 = __builtin_bit_cast(f16x2, v01);
      f16x2 p23 = __builtin_bit_cast(f16x2, v23);
      zg0[L][0] = (float)p01[0];
      zg0[L][1] = (float)p01[1];
      zg0[L][2] = (float)p23[0];
      zg0[L][3] = (float)p23[1];
      if (quad == 0) {
        unsigned w01 = Zp[(size_t)(prb + 8) * BS + bcol];
        unsigned w23 = Zp[(size_t)(prb + 9) * BS + bcol];
        f16x2 q01 = __builtin_bit_cast(f16x2, w01);
        f16x2 q23 = __builtin_bit_cast(f16x2, w23);
        zg1[L][0] = (float)q01[0];
        zg1[L][1] = (float)q01[1];
        zg1[L][2] = (float)q23[0];
        zg1[L][3] = (float)q23[1];
      } else {
        zg1[L][0] = zg1[L][1] = zg1[L][2] = zg1[L][3] = 0.f;
      }
    }

    // ---- layer 1: z[32ch x 16b] = W1(i) (32x64) . sL (64x16) ----
    {
      f32x4 z0 = (f32x4){0.f, 0.f, 0.f, 0.f};
      f32x4 z1 = (f32x4){0.f, 0.f, 0.f, 0.f};
      const int KS1 = (i + 31) >> 5;
      const f16* w0 = W1T + (size_t)(i * 2) * 2 * 512 + lane * 8;
      for (int ks = 0; ks < KS1; ++ks) {
        f16x8 bf = *(const f16x8*)&sL[l15][quad * 8 + 32 * ks];
        if (t > 0 && ks == ((i - 1) >> 5) && quad == (((I & 31) + t - 1) >> 3))
          bf[(t - 1) & 7] = (f16)bitv;  // freshest bit, not yet LDS-visible
        f16x8 a0 = *(const f16x8*)(w0 + ks * 512);
        f16x8 a1 = *(const f16x8*)(w0 + (2 + ks) * 512);
        z0 = __builtin_amdgcn_mfma_f32_16x16x32_f16(a0, bf, z0, 0, 0, 0);
        z1 = __builtin_amdgcn_mfma_f32_16x16x32_f16(a1, bf, z1, 0, 0, 0);
      }
      f16x4 o0;
#pragma unroll
      for (int r = 0; r < 4; ++r) o0[r] = (f16)sigm(z0[r]);
      *(f16x4*)&aL[0][l15][t * HC + quad * 4] = o0;
      if (quad == 0) {
        f16x4 o1;
#pragma unroll
        for (int r = 0; r < 4; ++r) o1[r] = (f16)sigm(z1[r]);
        *(f16x4*)&aL[0][l15][t * HC + 16] = o1;
      }
    }
    __syncthreads();

    // ---- layers 2..5: z = W(L,i) (32xK) . aL[L] (Kx16), then += Zg ----
    const int KS = (HC * (t + 1) + 31) >> 5;  // compile-time under unroll
    float a5o0[4], a5o1[4];
#pragma unroll
    for (int L = 0; L < 4; ++L) {
      f32x4 z0 = (f32x4){0.f, 0.f, 0.f, 0.f};
      f32x4 z1 = (f32x4){0.f, 0.f, 0.f, 0.f};
      const f16* wb = WsT + (size_t)((L * NS + i) * 2) * 5 * 512 + lane * 8;
#pragma unroll
      for (int ks = 0; ks < KS; ++ks) {
        f16x8 bf = *(const f16x8*)&aL[L][l15][quad * 8 + 32 * ks];
        f16x8 a0 = *(const f16x8*)(wb + ks * 512);
        f16x8 a1 = *(const f16x8*)(wb + (5 + ks) * 512);
        z0 = __builtin_amdgcn_mfma_f32_16x16x32_f16(a0, bf, z0, 0, 0, 0);
        z1 = __builtin_amdgcn_mfma_f32_16x16x32_f16(a1, bf, z1, 0, 0, 0);
      }
      f16x4 o0;
#pragma unroll
      for (int r = 0; r < 4; ++r) {
        float v = sigm(z0[r] + zg0[L][r]);
        o0[r] = (f16)v;
        if (L == 3) a5o0[r] = v;
      }
      *(f16x4*)&aL[L + 1][l15][t * HC + quad * 4] = o0;
      {
        f16x4 o1;
#pragma unroll
        for (int r = 0; r < 4; ++r) {
          float v = sigm(z1[r] + zg1[L][r]);
          o1[r] = (f16)v;
          if (L == 3) a5o1[r] = v;
        }
        if (quad == 0) *(f16x4*)&aL[L + 1][l15][t * HC + 16] = o1;
      }
      if (L < 3) __syncthreads();  // aL[4] never cross-read before writeout
    }

    // ---- z6: B-frag = fresh a5 only (W6bT zero-masks k>=20) via shfl ----
    {
      unsigned p0 = pk2(a5o0[0], a5o0[1]);
      unsigned p1 = pk2(a5o0[2], a5o0[3]);
      unsigned p2 = pk2(a5o1[0], a5o1[1]);
      unsigned p3 = pk2(a5o1[2], a5o1[3]);
      int src1 = (((quad * 2) & 3) << 4) + l15;
      int src2 = src1 + 16;
      unsigned d0 = (unsigned)__shfl((int)p0, src1, 64);
      unsigned d1 = (unsigned)__shfl((int)p1, src1, 64);
      unsigned d2 = (unsigned)__shfl((int)p0, src2, 64);
      unsigned d3 = (unsigned)__shfl((int)p1, src2, 64);
      unsigned e0 = (unsigned)__shfl((int)p2, src1, 64);
      unsigned e1 = (unsigned)__shfl((int)p3, src1, 64);
      u32x4 bv = (quad < 2) ? (u32x4){d0, d1, d2, d3} : (u32x4){e0, e1, e0, e1};
      f16x8 b5 = __builtin_bit_cast(f16x8, bv);
      f16x8 a6 = *(const f16x8*)(W6bT + (size_t)(m * 8 + t) * 512 + lane * 8);
      acc6 = __builtin_amdgcn_mfma_f32_16x16x32_f16(a6, b5, acc6, 0, 0, 0);
      // extract row t (owner quad = t>>2, reg t&3; static under unroll)
      float x = sigm(acc6[t & 3]);
      if (quad == (t >> 2)) {
        outp[(size_t)bg * NS + i] = x;  // final output col i == sampling-time x
        sL[l15][i] = (f16)((x >= uv[t]) ? 1.0f : -1.0f);
      }
      float xall = __shfl(x, ((t >> 2) << 4) + l15, 64);
      bitv = (xall >= uv[t]) ? 1.0f : -1.0f;
    }
    // no end-of-t barrier: t+1 L1 gets the fresh bit from bitv; older sL writes
    // are >= 4 syncs old; aL[4] writes only read after the final barrier.
  }
  __syncthreads();

  // ---- bulk writeout: block activations -> global AH ([L][g][b][e]), s bits ----
  for (int w = lane; w < 5 * 20 * BT; w += 64) {
    int rr = w & 15;
    int q = w >> 4;            // 0..99
    int L = q / 20, x8 = q % 20;
    f16x8 v = *(const f16x8*)&aL[L][rr][x8 * 8];
    int gg = ((HC * I) >> 3) + x8;
    *(f16x8*)(AH + ((size_t)(L * 160 + gg) * BS + blockIdx.x * BT + rr) * 8) = v;
  }
  if (lane < BT) {
    unsigned long long pk = 0;
#pragma unroll
    for (int e = 0; e < 8; ++e) {
      float f = (float)sL[lane][I + e];
      unsigned char c = (unsigned char)(signed char)((f >= 0.f) ? 1 : -1);
      pk |= (unsigned long long)c << (8 * e);
    }
    *(unsigned long long*)(s_ws + (size_t)(blockIdx.x * BT + lane) * NS + I) = pk;
  }
}

// ---------------------------------------------------------------------------
extern "C" void kernel_launch(void* const* d_in, const int* in_sizes, int n_in,
                              void* d_out, int out_size, void* d_ws, size_t ws_size,
                              hipStream_t stream) {
  (void)in_sizes; (void)n_in; (void)out_size;
  const float* u  = (const float*)d_in[1];
  const float* W1 = (const float*)d_in[2];
  const float* W2 = (const float*)d_in[3];
  const float* W3 = (const float*)d_in[4];
  const float* W4 = (const float*)d_in[5];
  const float* W5 = (const float*)d_in[6];
  const float* W6 = (const float*)d_in[7];
  float* outp = (float*)d_out;

  const size_t wpTEls  = (size_t)4 * 80 * 40 * 512;      // 6.55M  hist A
  const size_t wsTEls  = (size_t)4 * NS * 2 * 5 * 512;   // 1.31M  seq A
  const size_t w1TEls  = (size_t)NS * 2 * 2 * 512;       // 131K   seq L1 A
  const size_t w6bTEls = (size_t)64 * 512;               // 33K    seq z6 A
  const size_t w6TEls  = (size_t)8 * 40 * 512;           // 164K   hist z6 A
  const size_t wEls = wpTEls + wsTEls + w1TEls + w6bTEls + w6TEls;
  const size_t wBytes = wEls * sizeof(f16);

  // per-row: AH 12800 + ZgH 1280 (pair-u32 f16) + Zg6 64 (f32) + s_ws 64 (i8)
  // = 14208 B -> BS = 16384 single chunk.
  size_t rem = (ws_size > wBytes + 4096) ? (ws_size - wBytes - 4096) : 0;
  long long bs = (long long)(rem / 14208);
  bs = (bs / 64) * 64;
  if (bs > NB) bs = NB;
  if (bs < 64) bs = 64;
  const int BS = (int)bs;

  f16* WpT   = (f16*)d_ws;
  f16* WsT   = WpT + wpTEls;
  f16* W1T   = WsT + wsTEls;
  f16* W6bT  = W1T + w1TEls;
  f16* W6T   = W6bT + w6bTEls;
  f16* AH    = W6T + w6TEls;
  f16* ZgH   = AH + (size_t)5 * 160 * BS * 8;            // [320 pairs][BS] u32
  float* Zg6 = (float*)(ZgH + (size_t)640 * BS);
  signed char* s_ws = (signed char*)(Zg6 + (size_t)16 * BS);

  prep<<<dim3(4 * HTOT + NS + 16), dim3(256), 0, stream>>>(
      W1, W2, W3, W4, W5, W6, WpT, WsT, W1T, W6bT, W6T);

  for (int c0 = 0; c0 < NB; c0 += BS) {
    int nr = NB - c0; if (nr > BS) nr = BS;
    for (int m = 0; m < NS / KB; ++m) {
      const int I = m * KB;
      gemm_hist<<<dim3(nr / 64, 5), dim3(256), 0, stream>>>(
          WpT, W6T, AH, ZgH, Zg6, I, BS);
      seq_block<<<dim3(nr / BT), dim3(64), 0, stream>>>(
          WsT, W1T, W6bT, AH, ZgH, Zg6, s_ws, u, outp, I, BS, c0);
    }
  }
}